// Round 1
// baseline (5576.767 us; speedup 1.0000x reference)
//
#include <hip/hip_runtime.h>

// Problem constants (match reference)
static const int NU = 100000;   // users
static const int NM = 20000;    // movies
static const int NE = 600000;   // edges
static const int FEAT = 64;
static const int HID = 128;
static const int OUTD = 64;

// ---------------- count + reciprocal ----------------
__global__ void k_count(const int* __restrict__ ui, const int* __restrict__ mi,
                        float* __restrict__ ucnt, float* __restrict__ mcnt, int E) {
    int e = blockIdx.x * blockDim.x + threadIdx.x;
    if (e < E) {
        atomicAdd(ucnt + ui[e], 1.0f);
        atomicAdd(mcnt + mi[e], 1.0f);
    }
}

__global__ void k_inv(float* __restrict__ v, int n) {
    int i = blockIdx.x * blockDim.x + threadIdx.x;
    if (i < n) v[i] = 1.0f / fmaxf(v[i], 1.0f);
}

// ---------------- per-edge scatter-add (one thread per (edge, col)) ----------------
template<int C>
__global__ void k_scatter(const float* __restrict__ src, const int* __restrict__ sidx,
                          const int* __restrict__ didx, float* __restrict__ acc, int E) {
    long long gid = (long long)blockIdx.x * blockDim.x + threadIdx.x;
    int e = (int)(gid / C);
    int c = (int)(gid % C);
    if (e >= E) return;
    int s = sidx[e];
    int d = didx[e];
    atomicAdd(acc + (size_t)d * C + c, src[(size_t)s * C + c]);
}

// ---------------- fused row GEMM: Y = [relu]( scale[r] * X @ W^T + vec + carry ) ----------------
// X: [N][K] f32, W: [H][K] f32 (row-major, PyTorch lin.weight layout), Y: [N][H]
// vec: [H] broadcast add (bias or precomputed c1); carry: [N][H] per-row add (may alias Y)
template<int K, int H, bool AVEC, bool CARRY, bool RELU, bool SCALE>
__global__ void k_gemm(const float* __restrict__ X, const float* __restrict__ W,
                       const float* __restrict__ vec, const float* __restrict__ carry,
                       const float* __restrict__ scale, float* __restrict__ Y, int N) {
    int r = blockIdx.x * blockDim.x + threadIdx.x;
    if (r >= N) return;

    float4 x[K / 4];
    const float4* Xr = reinterpret_cast<const float4*>(X) + (size_t)r * (K / 4);
#pragma unroll
    for (int i = 0; i < K / 4; ++i) x[i] = Xr[i];
    if (SCALE) {
        float s = scale[r];
#pragma unroll
        for (int i = 0; i < K / 4; ++i) {
            x[i].x *= s; x[i].y *= s; x[i].z *= s; x[i].w *= s;
        }
    }

    const float4* W4 = reinterpret_cast<const float4*>(W);
    float4* Yr = reinterpret_cast<float4*>(Y + (size_t)r * H);
    const float4* Cr = reinterpret_cast<const float4*>(CARRY ? carry + (size_t)r * H : Y);

    for (int h4 = 0; h4 < H / 4; ++h4) {
        float out[4];
#pragma unroll
        for (int hh = 0; hh < 4; ++hh) {
            int h = h4 * 4 + hh;
            float4 a = make_float4(0.f, 0.f, 0.f, 0.f);
            const float4* Wr = W4 + (size_t)h * (K / 4);
#pragma unroll
            for (int i = 0; i < K / 4; ++i) {
                float4 w = Wr[i];
                a.x += x[i].x * w.x;
                a.y += x[i].y * w.y;
                a.z += x[i].z * w.z;
                a.w += x[i].w * w.w;
            }
            float acc = (a.x + a.y) + (a.z + a.w);
            if (AVEC) acc += vec[h];
            out[hh] = acc;
        }
        float4 o = make_float4(out[0], out[1], out[2], out[3]);
        if (CARRY) {
            float4 c = Cr[h4];
            o.x += c.x; o.y += c.y; o.z += c.z; o.w += c.w;
        }
        if (RELU) {
            o.x = fmaxf(o.x, 0.f); o.y = fmaxf(o.y, 0.f);
            o.z = fmaxf(o.z, 0.f); o.w = fmaxf(o.w, 0.f);
        }
        Yr[h4] = o;
    }
}

// ---------------- new_index output (ints stored as float values) ----------------
__global__ void k_index(const int* __restrict__ t, float* __restrict__ o, int n, int nu) {
    int i = blockIdx.x * blockDim.x + threadIdx.x;
    if (i < n) {
        o[i] = (float)t[i];
        o[n + i] = (float)(t[n + i] + nu);
    }
}

extern "C" void kernel_launch(void* const* d_in, const int* in_sizes, int n_in,
                              void* d_out, int out_size, void* d_ws, size_t ws_size,
                              hipStream_t stream) {
    const float* movie_x  = (const float*)d_in[0];
    const int*   user_idx = (const int*)d_in[1];
    const int*   movie_idx= (const int*)d_in[2];
    const int*   tuples   = (const int*)d_in[3];
    const float* user_emb = (const float*)d_in[4];
    const float* W1l = (const float*)d_in[5];
    const float* b1  = (const float*)d_in[6];
    const float* W1r = (const float*)d_in[7];
    const float* W2l = (const float*)d_in[8];
    const float* b2  = (const float*)d_in[9];
    const float* W2r = (const float*)d_in[10];
    const float* W3l = (const float*)d_in[11];
    const float* b3  = (const float*)d_in[12];
    const float* W3r = (const float*)d_in[13];
    const float* Wlin1 = (const float*)d_in[14];
    const float* blin1 = (const float*)d_in[15];
    const float* Wlin2 = (const float*)d_in[16];
    const float* blin2 = (const float*)d_in[17];

    float* out = (float*)d_out;
    float* ws  = (float*)d_ws;

    // workspace layout (in floats)
    const size_t off_c1   = 0;                    // 128
    const size_t off_ucnt = 128;                  // 100000 (becomes inv count)
    const size_t off_mcnt = 100128;               // 20000
    const size_t off_A    = 120128;               // user_sum1 [100000][64]
    const size_t off_B    = off_A + (size_t)NU * FEAT;   // user_x / user_sum3 [100000][128]
    const size_t off_C    = off_B + (size_t)NU * HID;    // t3 / user_z [100000][128]
    const size_t off_D    = off_C + (size_t)NU * HID;    // movie_sum2 [20000][128]
    const size_t off_E    = off_D + (size_t)NM * HID;    // t2 / movie_z [20000][128]

    float* c1    = ws + off_c1;
    float* ucnt  = ws + off_ucnt;
    float* mcnt  = ws + off_mcnt;
    float* A     = ws + off_A;
    float* B     = ws + off_B;
    float* Cb    = ws + off_C;
    float* D     = ws + off_D;
    float* Eb    = ws + off_E;

    // ---- zero accumulators ----
    hipMemsetAsync(ucnt, 0, (size_t)(NU + NM) * 4, stream);
    hipMemsetAsync(A, 0, (size_t)NU * FEAT * 4, stream);
    hipMemsetAsync(D, 0, (size_t)NM * HID * 4, stream);

    // ---- counts + reciprocals ----
    k_count<<<(NE + 255) / 256, 256, 0, stream>>>(user_idx, movie_idx, ucnt, mcnt, NE);
    k_inv<<<(NU + NM + 255) / 256, 256, 0, stream>>>(ucnt, NU + NM);

    // ---- c1 = b1 + user_emb @ W1r^T  (rank-1 collapse of x_dst term) ----
    k_gemm<HID, HID, true, false, false, false><<<1, 256, 0, stream>>>(
        user_emb, W1r, b1, nullptr, nullptr, c1, 1);

    // ---- conv1: scatter movie_x over (movie->user) edges, then node update ----
    {
        long long tot = (long long)NE * FEAT;
        k_scatter<FEAT><<<(int)((tot + 255) / 256), 256, 0, stream>>>(
            movie_x, movie_idx, user_idx, A, NE);
    }
    // user_x = relu(mean1 @ W1l^T + c1)
    k_gemm<FEAT, HID, true, false, true, true><<<(NU + 255) / 256, 256, 0, stream>>>(
        A, W1l, c1, nullptr, ucnt, B, NU);

    // ---- conv2: scatter user_x over (user->movie) edges ----
    {
        long long tot = (long long)NE * HID;
        k_scatter<HID><<<(int)((tot + 255) / 256), 256, 0, stream>>>(
            B, user_idx, movie_idx, D, NE);
    }
    // t2 = movie_x @ W2r^T + b2
    k_gemm<FEAT, HID, true, false, false, false><<<(NM + 255) / 256, 256, 0, stream>>>(
        movie_x, W2r, b2, nullptr, nullptr, Eb, NM);
    // movie_z = relu(mean2 @ W2l^T + t2)   (in-place over Eb)
    k_gemm<HID, HID, false, true, true, true><<<(NM + 255) / 256, 256, 0, stream>>>(
        D, W2l, nullptr, Eb, mcnt, Eb, NM);
    // z_movie = movie_z @ Wlin2^T + blin2  -> out rows [100000, 120000)
    k_gemm<HID, OUTD, true, false, false, false><<<(NM + 255) / 256, 256, 0, stream>>>(
        Eb, Wlin2, blin2, nullptr, nullptr, out + (size_t)NU * OUTD, NM);

    // ---- conv3: t3 = user_x @ W3r^T + b3 (consume user_x before reusing B) ----
    k_gemm<HID, HID, true, false, false, false><<<(NU + 255) / 256, 256, 0, stream>>>(
        B, W3r, b3, nullptr, nullptr, Cb, NU);
    // re-zero B as user_sum3, scatter movie_z over (movie->user) edges
    hipMemsetAsync(B, 0, (size_t)NU * HID * 4, stream);
    {
        long long tot = (long long)NE * HID;
        k_scatter<HID><<<(int)((tot + 255) / 256), 256, 0, stream>>>(
            Eb, movie_idx, user_idx, B, NE);
    }
    // user_z = relu(mean3 @ W3l^T + t3)   (in-place over Cb)
    k_gemm<HID, HID, false, true, true, true><<<(NU + 255) / 256, 256, 0, stream>>>(
        B, W3l, nullptr, Cb, ucnt, Cb, NU);
    // z_user = user_z @ Wlin1^T + blin1 -> out rows [0, 100000)
    k_gemm<HID, OUTD, true, false, false, false><<<(NU + 255) / 256, 256, 0, stream>>>(
        Cb, Wlin1, blin1, nullptr, nullptr, out, NU);

    // ---- new_index ----
    k_index<<<(100000 + 255) / 256, 256, 0, stream>>>(
        tuples, out + (size_t)(NU + NM) * OUTD, 100000, NU);
}

// Round 2
// 984.199 us; speedup vs baseline: 5.6663x; 5.6663x over previous
//
#include <hip/hip_runtime.h>

// Problem constants (match reference)
static const int NU = 100000;   // users
static const int NM = 20000;    // movies
static const int NE = 600000;   // edges
static const int FEAT = 64;
static const int HID = 128;
static const int OUTD = 64;

// ---------------- count + reciprocal ----------------
__global__ void k_count(const int* __restrict__ ui, const int* __restrict__ mi,
                        float* __restrict__ ucnt, float* __restrict__ mcnt, int E) {
    int e = blockIdx.x * blockDim.x + threadIdx.x;
    if (e < E) {
        atomicAdd(ucnt + ui[e], 1.0f);
        atomicAdd(mcnt + mi[e], 1.0f);
    }
}

__global__ void k_inv(float* __restrict__ v, int n) {
    int i = blockIdx.x * blockDim.x + threadIdx.x;
    if (i < n) v[i] = 1.0f / fmaxf(v[i], 1.0f);
}

// ---------------- per-edge scatter-add (one thread per (edge, col)) ----------------
template<int C>
__global__ void k_scatter(const float* __restrict__ src, const int* __restrict__ sidx,
                          const int* __restrict__ didx, float* __restrict__ acc, int E) {
    long long gid = (long long)blockIdx.x * blockDim.x + threadIdx.x;
    int e = (int)(gid / C);
    int c = (int)(gid % C);
    if (e >= E) return;
    int s = sidx[e];
    int d = didx[e];
    atomicAdd(acc + (size_t)d * C + c, src[(size_t)s * C + c]);
}

// ---------------- tiled fused GEMM: Y = [relu]( scale[r] * X @ W^T + vec + carry ) ----------------
// X: [N][K] f32, W: [BN][K] f32 row-major, Y: [N][BN]
// Block: 256 threads (16x16), tile 64 rows x BN cols, BK=32, micro 4 x (BN/16).
template<int K, int BN, bool AVEC, bool CARRY, bool RELU, bool SCALE>
__global__ __launch_bounds__(256) void k_gemm_t(
        const float* __restrict__ X, const float* __restrict__ W,
        const float* __restrict__ vec, const float* __restrict__ carry,
        const float* __restrict__ scale, float* __restrict__ Y, int N) {
    constexpr int BM = 64;
    constexpr int BK = 32;
    constexpr int MN = BN / 16;          // 8 (BN=128) or 4 (BN=64)
    constexpr int XP = BM + 4;           // padded stride (68 floats = 17x16B, keeps b128 align)
    constexpr int WP = BN + 4;           // 132 or 68, both 16B-aligned strides

    __shared__ float XsT[BK][XP];        // k-major X tile
    __shared__ float WsT[BK][WP];        // k-major W tile (WsT[k][c] = W[c][k])

    const int tid = threadIdx.x;
    const int tx = tid & 15;
    const int ty = tid >> 4;
    const int r0 = blockIdx.x * BM;

    float acc[4][MN];
#pragma unroll
    for (int i = 0; i < 4; ++i)
#pragma unroll
        for (int j = 0; j < MN; ++j) acc[i][j] = 0.f;

    for (int k0 = 0; k0 < K; k0 += BK) {
        // ---- stage X tile (transposed), coalesced float4 reads ----
#pragma unroll
        for (int s = 0; s < 2; ++s) {
            int r = (tid >> 3) + s * 32;          // 0..63
            int kk = (tid & 7) * 4;               // 0..28
            float4 v = make_float4(0.f, 0.f, 0.f, 0.f);
            int gr = r0 + r;
            if (gr < N) {
                v = *reinterpret_cast<const float4*>(X + (size_t)gr * K + k0 + kk);
                if (SCALE) {
                    float sc = scale[gr];
                    v.x *= sc; v.y *= sc; v.z *= sc; v.w *= sc;
                }
            }
            XsT[kk + 0][r] = v.x;
            XsT[kk + 1][r] = v.y;
            XsT[kk + 2][r] = v.z;
            XsT[kk + 3][r] = v.w;
        }
        // ---- stage W tile (transposed) ----
#pragma unroll
        for (int s = 0; s < BN / 32; ++s) {
            int c = (tid >> 3) + s * 32;
            int kk = (tid & 7) * 4;
            float4 v = *reinterpret_cast<const float4*>(W + (size_t)c * K + k0 + kk);
            WsT[kk + 0][c] = v.x;
            WsT[kk + 1][c] = v.y;
            WsT[kk + 2][c] = v.z;
            WsT[kk + 3][c] = v.w;
        }
        __syncthreads();

        // ---- inner product: b128 LDS reads, register micro-tile ----
#pragma unroll 8
        for (int kk = 0; kk < BK; ++kk) {
            float4 xv = *reinterpret_cast<const float4*>(&XsT[kk][ty * 4]);
            float xr[4] = {xv.x, xv.y, xv.z, xv.w};
            float wr[MN];
            {
                float4 wa = *reinterpret_cast<const float4*>(&WsT[kk][tx * MN]);
                wr[0] = wa.x; wr[1] = wa.y; wr[2] = wa.z; wr[3] = wa.w;
                if (MN == 8) {
                    float4 wb = *reinterpret_cast<const float4*>(&WsT[kk][tx * MN + 4]);
                    wr[4] = wb.x; wr[5] = wb.y; wr[6] = wb.z; wr[7] = wb.w;
                }
            }
#pragma unroll
            for (int i = 0; i < 4; ++i)
#pragma unroll
                for (int j = 0; j < MN; ++j)
                    acc[i][j] += xr[i] * wr[j];
        }
        __syncthreads();
    }

    // ---- epilogue: coalesced float4 stores ----
#pragma unroll
    for (int i = 0; i < 4; ++i) {
        int r = r0 + ty * 4 + i;
        if (r >= N) continue;
#pragma unroll
        for (int j4 = 0; j4 < MN / 4; ++j4) {
            int c = tx * MN + j4 * 4;
            float4 o = make_float4(acc[i][j4 * 4 + 0], acc[i][j4 * 4 + 1],
                                   acc[i][j4 * 4 + 2], acc[i][j4 * 4 + 3]);
            if (AVEC) {
                const float4 vv = *reinterpret_cast<const float4*>(vec + c);
                o.x += vv.x; o.y += vv.y; o.z += vv.z; o.w += vv.w;
            }
            if (CARRY) {
                const float4 cv = *reinterpret_cast<const float4*>(carry + (size_t)r * BN + c);
                o.x += cv.x; o.y += cv.y; o.z += cv.z; o.w += cv.w;
            }
            if (RELU) {
                o.x = fmaxf(o.x, 0.f); o.y = fmaxf(o.y, 0.f);
                o.z = fmaxf(o.z, 0.f); o.w = fmaxf(o.w, 0.f);
            }
            *reinterpret_cast<float4*>(Y + (size_t)r * BN + c) = o;
        }
    }
}

// ---------------- new_index output (ints stored as float values) ----------------
__global__ void k_index(const int* __restrict__ t, float* __restrict__ o, int n, int nu) {
    int i = blockIdx.x * blockDim.x + threadIdx.x;
    if (i < n) {
        o[i] = (float)t[i];
        o[n + i] = (float)(t[n + i] + nu);
    }
}

extern "C" void kernel_launch(void* const* d_in, const int* in_sizes, int n_in,
                              void* d_out, int out_size, void* d_ws, size_t ws_size,
                              hipStream_t stream) {
    const float* movie_x  = (const float*)d_in[0];
    const int*   user_idx = (const int*)d_in[1];
    const int*   movie_idx= (const int*)d_in[2];
    const int*   tuples   = (const int*)d_in[3];
    const float* user_emb = (const float*)d_in[4];
    const float* W1l = (const float*)d_in[5];
    const float* b1  = (const float*)d_in[6];
    const float* W1r = (const float*)d_in[7];
    const float* W2l = (const float*)d_in[8];
    const float* b2  = (const float*)d_in[9];
    const float* W2r = (const float*)d_in[10];
    const float* W3l = (const float*)d_in[11];
    const float* b3  = (const float*)d_in[12];
    const float* W3r = (const float*)d_in[13];
    const float* Wlin1 = (const float*)d_in[14];
    const float* blin1 = (const float*)d_in[15];
    const float* Wlin2 = (const float*)d_in[16];
    const float* blin2 = (const float*)d_in[17];

    float* out = (float*)d_out;
    float* ws  = (float*)d_ws;

    // workspace layout (in floats)
    const size_t off_c1   = 0;                    // 128
    const size_t off_ucnt = 128;                  // 100000 (becomes inv count)
    const size_t off_mcnt = 100128;               // 20000
    const size_t off_A    = 120128;               // user_sum1 [100000][64]
    const size_t off_B    = off_A + (size_t)NU * FEAT;   // user_x / user_sum3 [100000][128]
    const size_t off_C    = off_B + (size_t)NU * HID;    // t3 / user_z [100000][128]
    const size_t off_D    = off_C + (size_t)NU * HID;    // movie_sum2 [20000][128]
    const size_t off_E    = off_D + (size_t)NM * HID;    // t2 / movie_z [20000][128]

    float* c1    = ws + off_c1;
    float* ucnt  = ws + off_ucnt;
    float* mcnt  = ws + off_mcnt;
    float* A     = ws + off_A;
    float* B     = ws + off_B;
    float* Cb    = ws + off_C;
    float* D     = ws + off_D;
    float* Eb    = ws + off_E;

    // ---- zero accumulators ----
    hipMemsetAsync(ucnt, 0, (size_t)(NU + NM) * 4, stream);
    hipMemsetAsync(A, 0, (size_t)NU * FEAT * 4, stream);
    hipMemsetAsync(D, 0, (size_t)NM * HID * 4, stream);

    // ---- counts + reciprocals ----
    k_count<<<(NE + 255) / 256, 256, 0, stream>>>(user_idx, movie_idx, ucnt, mcnt, NE);
    k_inv<<<(NU + NM + 255) / 256, 256, 0, stream>>>(ucnt, NU + NM);

    // ---- c1 = b1 + user_emb @ W1r^T  (rank-1 collapse of x_dst term) ----
    k_gemm_t<HID, HID, true, false, false, false><<<1, 256, 0, stream>>>(
        user_emb, W1r, b1, nullptr, nullptr, c1, 1);

    // ---- conv1: scatter movie_x over (movie->user) edges, then node update ----
    {
        long long tot = (long long)NE * FEAT;
        k_scatter<FEAT><<<(int)((tot + 255) / 256), 256, 0, stream>>>(
            movie_x, movie_idx, user_idx, A, NE);
    }
    // user_x = relu(mean1 @ W1l^T + c1)
    k_gemm_t<FEAT, HID, true, false, true, true><<<(NU + 63) / 64, 256, 0, stream>>>(
        A, W1l, c1, nullptr, ucnt, B, NU);

    // ---- conv2: scatter user_x over (user->movie) edges ----
    {
        long long tot = (long long)NE * HID;
        k_scatter<HID><<<(int)((tot + 255) / 256), 256, 0, stream>>>(
            B, user_idx, movie_idx, D, NE);
    }
    // t2 = movie_x @ W2r^T + b2
    k_gemm_t<FEAT, HID, true, false, false, false><<<(NM + 63) / 64, 256, 0, stream>>>(
        movie_x, W2r, b2, nullptr, nullptr, Eb, NM);
    // movie_z = relu(mean2 @ W2l^T + t2)   (in-place over Eb)
    k_gemm_t<HID, HID, false, true, true, true><<<(NM + 63) / 64, 256, 0, stream>>>(
        D, W2l, nullptr, Eb, mcnt, Eb, NM);
    // z_movie = movie_z @ Wlin2^T + blin2  -> out rows [100000, 120000)
    k_gemm_t<HID, OUTD, true, false, false, false><<<(NM + 63) / 64, 256, 0, stream>>>(
        Eb, Wlin2, blin2, nullptr, nullptr, out + (size_t)NU * OUTD, NM);

    // ---- conv3: t3 = user_x @ W3r^T + b3 (consume user_x before reusing B) ----
    k_gemm_t<HID, HID, true, false, false, false><<<(NU + 63) / 64, 256, 0, stream>>>(
        B, W3r, b3, nullptr, nullptr, Cb, NU);
    // re-zero B as user_sum3, scatter movie_z over (movie->user) edges
    hipMemsetAsync(B, 0, (size_t)NU * HID * 4, stream);
    {
        long long tot = (long long)NE * HID;
        k_scatter<HID><<<(int)((tot + 255) / 256), 256, 0, stream>>>(
            Eb, movie_idx, user_idx, B, NE);
    }
    // user_z = relu(mean3 @ W3l^T + t3)   (in-place over Cb)
    k_gemm_t<HID, HID, false, true, true, true><<<(NU + 63) / 64, 256, 0, stream>>>(
        B, W3l, nullptr, Cb, ucnt, Cb, NU);
    // z_user = user_z @ Wlin1^T + blin1 -> out rows [0, 100000)
    k_gemm_t<HID, OUTD, true, false, false, false><<<(NU + 63) / 64, 256, 0, stream>>>(
        Cb, Wlin1, blin1, nullptr, nullptr, out, NU);

    // ---- new_index ----
    k_index<<<(100000 + 255) / 256, 256, 0, stream>>>(
        tuples, out + (size_t)(NU + NM) * OUTD, 100000, NU);
}

// Round 3
// 481.733 us; speedup vs baseline: 11.5765x; 2.0430x over previous
//
#include <hip/hip_runtime.h>

// Problem constants (match reference)
static const int NU = 100000;   // users
static const int NM = 20000;    // movies
static const int NE = 600000;   // edges
static const int FEAT = 64;
static const int HID = 128;
static const int OUTD = 64;
static const int NTOT = NU + NM;        // 120000 destination nodes (users then movies)
static const int NLIST = 2 * NE;        // 1.2M list slots (user-dst edges, then movie-dst)

// ---------------- degree count (int) ----------------
__global__ void k_count_i(const int* __restrict__ ui, const int* __restrict__ mi,
                          int* __restrict__ cnt, int E) {
    int e = blockIdx.x * blockDim.x + threadIdx.x;
    if (e < E) {
        atomicAdd(cnt + ui[e], 1);
        atomicAdd(cnt + NU + mi[e], 1);
    }
}

// ---------------- 3-kernel exclusive scan over NTOT ints ----------------
// scan1: 1024 items/block (256 thr x 4), exclusive within block + block sums
__global__ __launch_bounds__(256) void k_scan1(const int* __restrict__ cnt,
                                               int* __restrict__ rp,
                                               int* __restrict__ bsum, int n) {
    __shared__ int s[256];
    const int tid = threadIdx.x;
    const int base = blockIdx.x * 1024 + tid * 4;
    int v[4];
#pragma unroll
    for (int j = 0; j < 4; ++j) v[j] = (base + j < n) ? cnt[base + j] : 0;
    int tot = v[0] + v[1] + v[2] + v[3];
    s[tid] = tot;
    __syncthreads();
#pragma unroll
    for (int off = 1; off < 256; off <<= 1) {
        int x = (tid >= off) ? s[tid - off] : 0;
        __syncthreads();
        s[tid] += x;
        __syncthreads();
    }
    int run = s[tid] - tot;   // exclusive prefix for this thread
#pragma unroll
    for (int j = 0; j < 4; ++j) {
        if (base + j < n) rp[base + j] = run;
        run += v[j];
    }
    if (tid == 255) bsum[blockIdx.x] = s[255];
}

// scan2: single block scans block sums (nb <= 128), writes rp[n] = total
__global__ __launch_bounds__(128) void k_scan2(int* __restrict__ bsum,
                                               int* __restrict__ rp, int nb, int n) {
    __shared__ int s[128];
    const int tid = threadIdx.x;
    int v = (tid < nb) ? bsum[tid] : 0;
    s[tid] = v;
    __syncthreads();
#pragma unroll
    for (int off = 1; off < 128; off <<= 1) {
        int x = (tid >= off) ? s[tid - off] : 0;
        __syncthreads();
        s[tid] += x;
        __syncthreads();
    }
    if (tid < nb) bsum[tid] = s[tid] - v;   // exclusive
    if (tid == 127) rp[n] = s[127];         // grand total
}

// scan3: add scanned block sums back
__global__ __launch_bounds__(256) void k_scan3(int* __restrict__ rp,
                                               const int* __restrict__ bsum, int n) {
    const int add = bsum[blockIdx.x];
    const int base = blockIdx.x * 1024 + threadIdx.x * 4;
#pragma unroll
    for (int j = 0; j < 4; ++j)
        if (base + j < n) rp[base + j] += add;
}

// ---------------- inverse degree (float) ----------------
__global__ void k_inv_f(const int* __restrict__ cnt, float* __restrict__ inv, int n) {
    int i = blockIdx.x * blockDim.x + threadIdx.x;
    if (i < n) inv[i] = 1.0f / (float)max(cnt[i], 1);
}

// ---------------- fill CSR adjacency (src index per slot) ----------------
__global__ void k_fill(const int* __restrict__ ui, const int* __restrict__ mi,
                       const int* __restrict__ rp, int* __restrict__ cur,
                       int* __restrict__ list, int E) {
    int e = blockIdx.x * blockDim.x + threadIdx.x;
    if (e >= E) return;
    int u = ui[e], m = mi[e];
    int su = atomicAdd(cur + u, 1);
    list[rp[u] + su] = m;               // user-dst edge: store movie src
    int g = NU + m;
    int sm = atomicAdd(cur + g, 1);
    list[rp[g] + sm] = u;               // movie-dst edge: store user src
}

// ---------------- gather-based segment mean ----------------
// One (C/4)-thread subgroup per destination node; accumulate neighbor rows in regs.
template<int C>
__global__ __launch_bounds__(256) void k_gather(const float* __restrict__ src,
                                                const int* __restrict__ rp,
                                                const int* __restrict__ list,
                                                const float* __restrict__ inv,
                                                float* __restrict__ dst,
                                                int base, int n) {
    constexpr int TPN = C / 4;          // threads per node (16 or 32)
    constexpr int NPB = 256 / TPN;      // nodes per block
    const int node = blockIdx.x * NPB + threadIdx.x / TPN;
    if (node >= n) return;
    const int c4 = (threadIdx.x % TPN) * 4;
    const int g = base + node;
    const int s = rp[g], e = rp[g + 1];

    float4 a = make_float4(0.f, 0.f, 0.f, 0.f);
    int i = s;
    for (; i + 1 < e; i += 2) {          // 2-edge unroll for MLP
        int r0 = list[i], r1 = list[i + 1];
        float4 v0 = *reinterpret_cast<const float4*>(src + (size_t)r0 * C + c4);
        float4 v1 = *reinterpret_cast<const float4*>(src + (size_t)r1 * C + c4);
        a.x += v0.x + v1.x; a.y += v0.y + v1.y;
        a.z += v0.z + v1.z; a.w += v0.w + v1.w;
    }
    if (i < e) {
        int r0 = list[i];
        float4 v0 = *reinterpret_cast<const float4*>(src + (size_t)r0 * C + c4);
        a.x += v0.x; a.y += v0.y; a.z += v0.z; a.w += v0.w;
    }
    const float sc = inv[g];
    float4 o = make_float4(a.x * sc, a.y * sc, a.z * sc, a.w * sc);
    *reinterpret_cast<float4*>(dst + (size_t)node * C + c4) = o;
}

// ---------------- tiled fused GEMM: Y = [relu]( X @ W^T + vec + carry ) ----------------
// X: [N][K] f32, W: [BN][K] f32 row-major, Y: [N][BN]
template<int K, int BN, bool AVEC, bool CARRY, bool RELU>
__global__ __launch_bounds__(256) void k_gemm_t(
        const float* __restrict__ X, const float* __restrict__ W,
        const float* __restrict__ vec, const float* __restrict__ carry,
        float* __restrict__ Y, int N) {
    constexpr int BM = 64;
    constexpr int BK = 32;
    constexpr int MN = BN / 16;          // 8 (BN=128) or 4 (BN=64)
    constexpr int XP = BM + 4;
    constexpr int WP = BN + 4;

    __shared__ float XsT[BK][XP];        // k-major X tile
    __shared__ float WsT[BK][WP];        // k-major W tile

    const int tid = threadIdx.x;
    const int tx = tid & 15;
    const int ty = tid >> 4;
    const int r0 = blockIdx.x * BM;

    float acc[4][MN];
#pragma unroll
    for (int i = 0; i < 4; ++i)
#pragma unroll
        for (int j = 0; j < MN; ++j) acc[i][j] = 0.f;

    for (int k0 = 0; k0 < K; k0 += BK) {
#pragma unroll
        for (int s = 0; s < 2; ++s) {
            int r = (tid >> 3) + s * 32;
            int kk = (tid & 7) * 4;
            float4 v = make_float4(0.f, 0.f, 0.f, 0.f);
            int gr = r0 + r;
            if (gr < N)
                v = *reinterpret_cast<const float4*>(X + (size_t)gr * K + k0 + kk);
            XsT[kk + 0][r] = v.x;
            XsT[kk + 1][r] = v.y;
            XsT[kk + 2][r] = v.z;
            XsT[kk + 3][r] = v.w;
        }
#pragma unroll
        for (int s = 0; s < BN / 32; ++s) {
            int c = (tid >> 3) + s * 32;
            int kk = (tid & 7) * 4;
            float4 v = *reinterpret_cast<const float4*>(W + (size_t)c * K + k0 + kk);
            WsT[kk + 0][c] = v.x;
            WsT[kk + 1][c] = v.y;
            WsT[kk + 2][c] = v.z;
            WsT[kk + 3][c] = v.w;
        }
        __syncthreads();

#pragma unroll 8
        for (int kk = 0; kk < BK; ++kk) {
            float4 xv = *reinterpret_cast<const float4*>(&XsT[kk][ty * 4]);
            float xr[4] = {xv.x, xv.y, xv.z, xv.w};
            float wr[MN];
            {
                float4 wa = *reinterpret_cast<const float4*>(&WsT[kk][tx * MN]);
                wr[0] = wa.x; wr[1] = wa.y; wr[2] = wa.z; wr[3] = wa.w;
                if (MN == 8) {
                    float4 wb = *reinterpret_cast<const float4*>(&WsT[kk][tx * MN + 4]);
                    wr[4] = wb.x; wr[5] = wb.y; wr[6] = wb.z; wr[7] = wb.w;
                }
            }
#pragma unroll
            for (int i = 0; i < 4; ++i)
#pragma unroll
                for (int j = 0; j < MN; ++j)
                    acc[i][j] += xr[i] * wr[j];
        }
        __syncthreads();
    }

#pragma unroll
    for (int i = 0; i < 4; ++i) {
        int r = r0 + ty * 4 + i;
        if (r >= N) continue;
#pragma unroll
        for (int j4 = 0; j4 < MN / 4; ++j4) {
            int c = tx * MN + j4 * 4;
            float4 o = make_float4(acc[i][j4 * 4 + 0], acc[i][j4 * 4 + 1],
                                   acc[i][j4 * 4 + 2], acc[i][j4 * 4 + 3]);
            if (AVEC) {
                const float4 vv = *reinterpret_cast<const float4*>(vec + c);
                o.x += vv.x; o.y += vv.y; o.z += vv.z; o.w += vv.w;
            }
            if (CARRY) {
                const float4 cv = *reinterpret_cast<const float4*>(carry + (size_t)r * BN + c);
                o.x += cv.x; o.y += cv.y; o.z += cv.z; o.w += cv.w;
            }
            if (RELU) {
                o.x = fmaxf(o.x, 0.f); o.y = fmaxf(o.y, 0.f);
                o.z = fmaxf(o.z, 0.f); o.w = fmaxf(o.w, 0.f);
            }
            *reinterpret_cast<float4*>(Y + (size_t)r * BN + c) = o;
        }
    }
}

// ---------------- new_index output ----------------
__global__ void k_index(const int* __restrict__ t, float* __restrict__ o, int n, int nu) {
    int i = blockIdx.x * blockDim.x + threadIdx.x;
    if (i < n) {
        o[i] = (float)t[i];
        o[n + i] = (float)(t[n + i] + nu);
    }
}

extern "C" void kernel_launch(void* const* d_in, const int* in_sizes, int n_in,
                              void* d_out, int out_size, void* d_ws, size_t ws_size,
                              hipStream_t stream) {
    const float* movie_x  = (const float*)d_in[0];
    const int*   user_idx = (const int*)d_in[1];
    const int*   movie_idx= (const int*)d_in[2];
    const int*   tuples   = (const int*)d_in[3];
    const float* user_emb = (const float*)d_in[4];
    const float* W1l = (const float*)d_in[5];
    const float* b1  = (const float*)d_in[6];
    const float* W1r = (const float*)d_in[7];
    const float* W2l = (const float*)d_in[8];
    const float* b2  = (const float*)d_in[9];
    const float* W2r = (const float*)d_in[10];
    const float* W3l = (const float*)d_in[11];
    const float* b3  = (const float*)d_in[12];
    const float* W3r = (const float*)d_in[13];
    const float* Wlin1 = (const float*)d_in[14];
    const float* blin1 = (const float*)d_in[15];
    const float* Wlin2 = (const float*)d_in[16];
    const float* blin2 = (const float*)d_in[17];

    float* out = (float*)d_out;
    float* ws  = (float*)d_ws;

    // ---- workspace layout (units of 4 bytes) ----
    const size_t off_c1  = 0;                         // 128 f
    const size_t off_inv = 128;                       // NTOT f
    const size_t off_int = off_inv + NTOT;            // int region begins
    int* icnt = (int*)(ws + off_int);                 // NTOT (also doubles: zeroed with cur)
    int* cur  = icnt + NTOT;                          // NTOT
    int* rp   = cur + NTOT;                           // NTOT + 1
    int* bsum = rp + NTOT + 64;                       // 128 (padded)
    int* list = bsum + 128;                           // NLIST
    const size_t off_f2 = off_int + (size_t)(NTOT * 2 + NTOT + 64 + 128 + 1) + NLIST;
    float* B  = ws + off_f2;                          // user_x / user_sum3 [NU][128]
    float* Cb = B + (size_t)NU * HID;                 // t3 / user_z [NU][128]
    float* A  = Cb;                                   // alias: mean1 [NU][64] dead before Cb written
    float* D  = Cb + (size_t)NU * HID;                // movie mean [NM][128]
    float* Eb = D + (size_t)NM * HID;                 // t2 / movie_z [NM][128]
    float* c1  = ws + off_c1;
    float* inv = ws + off_inv;

    const int NBLK = (NTOT + 1023) / 1024;            // 118

    // ---- build CSR: count -> scan -> inv -> fill ----
    hipMemsetAsync(icnt, 0, (size_t)NTOT * 2 * sizeof(int), stream);  // icnt + cur
    k_count_i<<<(NE + 255) / 256, 256, 0, stream>>>(user_idx, movie_idx, icnt, NE);
    k_scan1<<<NBLK, 256, 0, stream>>>(icnt, rp, bsum, NTOT);
    k_scan2<<<1, 128, 0, stream>>>(bsum, rp, NBLK, NTOT);
    k_scan3<<<NBLK, 256, 0, stream>>>(rp, bsum, NTOT);
    k_inv_f<<<(NTOT + 255) / 256, 256, 0, stream>>>(icnt, inv, NTOT);
    k_fill<<<(NE + 255) / 256, 256, 0, stream>>>(user_idx, movie_idx, rp, cur, list, NE);

    // ---- c1 = b1 + user_emb @ W1r^T (rank-1 collapse) ----
    k_gemm_t<HID, HID, true, false, false><<<1, 256, 0, stream>>>(
        user_emb, W1r, b1, nullptr, c1, 1);

    // ---- conv1: gather mean of movie_x into A, then user_x = relu(A@W1l^T + c1) ----
    k_gather<FEAT><<<(NU + 15) / 16, 256, 0, stream>>>(movie_x, rp, list, inv, A, 0, NU);
    k_gemm_t<FEAT, HID, true, false, true><<<(NU + 63) / 64, 256, 0, stream>>>(
        A, W1l, c1, nullptr, B, NU);

    // ---- conv2: gather mean of user_x into D ----
    k_gather<HID><<<(NM + 7) / 8, 256, 0, stream>>>(B, rp, list, inv, D, NU, NM);
    // t2 = movie_x @ W2r^T + b2
    k_gemm_t<FEAT, HID, true, false, false><<<(NM + 63) / 64, 256, 0, stream>>>(
        movie_x, W2r, b2, nullptr, Eb, NM);
    // movie_z = relu(D @ W2l^T + t2)  (in-place over Eb)
    k_gemm_t<HID, HID, false, true, true><<<(NM + 63) / 64, 256, 0, stream>>>(
        D, W2l, nullptr, Eb, Eb, NM);
    // z_movie = movie_z @ Wlin2^T + blin2
    k_gemm_t<HID, OUTD, true, false, false><<<(NM + 63) / 64, 256, 0, stream>>>(
        Eb, Wlin2, blin2, nullptr, out + (size_t)NU * OUTD, NM);

    // ---- conv3: t3 = user_x @ W3r^T + b3 (consumes B; then B reused as gather dst) ----
    k_gemm_t<HID, HID, true, false, false><<<(NU + 63) / 64, 256, 0, stream>>>(
        B, W3r, b3, nullptr, Cb, NU);
    k_gather<HID><<<(NU + 7) / 8, 256, 0, stream>>>(Eb, rp, list, inv, B, 0, NU);
    // user_z = relu(B @ W3l^T + t3)  (in-place over Cb)
    k_gemm_t<HID, HID, false, true, true><<<(NU + 63) / 64, 256, 0, stream>>>(
        B, W3l, nullptr, Cb, Cb, NU);
    // z_user = user_z @ Wlin1^T + blin1
    k_gemm_t<HID, OUTD, true, false, false><<<(NU + 63) / 64, 256, 0, stream>>>(
        Cb, Wlin1, blin1, nullptr, out, NU);

    // ---- new_index ----
    k_index<<<(100000 + 255) / 256, 256, 0, stream>>>(
        tuples, out + (size_t)(NU + NM) * OUTD, 100000, NU);
}

// Round 4
// 364.476 us; speedup vs baseline: 15.3008x; 1.3217x over previous
//
#include <hip/hip_runtime.h>

typedef __attribute__((ext_vector_type(8))) short short8;   // 8 bf16 (4 VGPR)
typedef __attribute__((ext_vector_type(4))) float f32x4;    // MFMA acc

static const int NU = 100000;
static const int NM = 20000;
static const int NE = 600000;
static const int FEAT = 64;
static const int HID = 128;
static const int OUTD = 64;
static const int NTOT = NU + NM;
static const int NLIST = 2 * NE;
static const int CVT_TOT = 81920 + NM * FEAT;   // weights + movie_x

__device__ inline float b2f(unsigned short h) {
    unsigned int u = ((unsigned int)h) << 16;
    float f; __builtin_memcpy(&f, &u, 4); return f;
}
__device__ inline unsigned short f2b(float f) {
    unsigned int u; __builtin_memcpy(&u, &f, 4);
    u += 0x7FFFu + ((u >> 16) & 1u);            // RNE
    return (unsigned short)(u >> 16);
}

// ---------------- degree count ----------------
__global__ void k_count_i(const int* __restrict__ ui, const int* __restrict__ mi,
                          int* __restrict__ cnt, int E) {
    int e = blockIdx.x * blockDim.x + threadIdx.x;
    if (e < E) {
        atomicAdd(cnt + ui[e], 1);
        atomicAdd(cnt + NU + mi[e], 1);
    }
}

// ---------------- 3-kernel exclusive scan ----------------
__global__ __launch_bounds__(256) void k_scan1(const int* __restrict__ cnt,
                                               int* __restrict__ rp,
                                               int* __restrict__ bsum, int n) {
    __shared__ int s[256];
    const int tid = threadIdx.x;
    const int base = blockIdx.x * 1024 + tid * 4;
    int v[4];
#pragma unroll
    for (int j = 0; j < 4; ++j) v[j] = (base + j < n) ? cnt[base + j] : 0;
    int tot = v[0] + v[1] + v[2] + v[3];
    s[tid] = tot;
    __syncthreads();
#pragma unroll
    for (int off = 1; off < 256; off <<= 1) {
        int x = (tid >= off) ? s[tid - off] : 0;
        __syncthreads();
        s[tid] += x;
        __syncthreads();
    }
    int run = s[tid] - tot;
#pragma unroll
    for (int j = 0; j < 4; ++j) {
        if (base + j < n) rp[base + j] = run;
        run += v[j];
    }
    if (tid == 255) bsum[blockIdx.x] = s[255];
}

__global__ __launch_bounds__(128) void k_scan2(int* __restrict__ bsum,
                                               int* __restrict__ rp, int nb, int n) {
    __shared__ int s[128];
    const int tid = threadIdx.x;
    int v = (tid < nb) ? bsum[tid] : 0;
    s[tid] = v;
    __syncthreads();
#pragma unroll
    for (int off = 1; off < 128; off <<= 1) {
        int x = (tid >= off) ? s[tid - off] : 0;
        __syncthreads();
        s[tid] += x;
        __syncthreads();
    }
    if (tid < nb) bsum[tid] = s[tid] - v;
    if (tid == 127) rp[n] = s[127];
}

__global__ __launch_bounds__(256) void k_scan3(int* __restrict__ rp,
                                               const int* __restrict__ bsum, int n) {
    const int add = bsum[blockIdx.x];
    const int base = blockIdx.x * 1024 + threadIdx.x * 4;
#pragma unroll
    for (int j = 0; j < 4; ++j)
        if (base + j < n) rp[base + j] += add;
}

__global__ void k_inv_f(const int* __restrict__ cnt, float* __restrict__ inv, int n) {
    int i = blockIdx.x * blockDim.x + threadIdx.x;
    if (i < n) inv[i] = 1.0f / (float)max(cnt[i], 1);
}

// ---------------- fill CSR adjacency ----------------
__global__ void k_fill(const int* __restrict__ ui, const int* __restrict__ mi,
                       const int* __restrict__ rp, int* __restrict__ cur,
                       int* __restrict__ list, int E) {
    int e = blockIdx.x * blockDim.x + threadIdx.x;
    if (e >= E) return;
    int u = ui[e], m = mi[e];
    int su = atomicAdd(cur + u, 1);
    list[rp[u] + su] = m;
    int g = NU + m;
    int sm = atomicAdd(cur + g, 1);
    list[rp[g] + sm] = u;
}

// ---------------- fp32 -> bf16 conversion (weights + movie_x, one launch) ----------------
__global__ void k_cvt(const float* __restrict__ w1l, const float* __restrict__ w2l,
                      const float* __restrict__ w2r, const float* __restrict__ w3l,
                      const float* __restrict__ w3r, const float* __restrict__ wl1,
                      const float* __restrict__ wl2, const float* __restrict__ mx,
                      unsigned short* __restrict__ dst) {
    int g = blockIdx.x * blockDim.x + threadIdx.x;
    if (g >= CVT_TOT) return;
    const float* s; int o;
    if      (g < 8192)   { s = w1l; o = g; }
    else if (g < 24576)  { s = w2l; o = g - 8192; }
    else if (g < 32768)  { s = w2r; o = g - 24576; }
    else if (g < 49152)  { s = w3l; o = g - 32768; }
    else if (g < 65536)  { s = w3r; o = g - 49152; }
    else if (g < 73728)  { s = wl1; o = g - 65536; }
    else if (g < 81920)  { s = wl2; o = g - 73728; }
    else                 { s = mx;  o = g - 81920; }
    dst[g] = f2b(s[o]);
}

// ---------------- c1 = b1 + user_emb @ W1r^T (fp32, rank-1 collapse) ----------------
__global__ void k_c1(const float* __restrict__ ue, const float* __restrict__ w1r,
                     const float* __restrict__ b1, float* __restrict__ c1) {
    int h = threadIdx.x;
    float a = 0.f;
#pragma unroll 16
    for (int k = 0; k < HID; ++k) a += ue[k] * w1r[h * HID + k];
    c1[h] = a + b1[h];
}

// ---------------- bf16 gather-based segment mean ----------------
template<int C>
__global__ __launch_bounds__(256) void k_gather_b(const unsigned short* __restrict__ src,
                                                  const int* __restrict__ rp,
                                                  const int* __restrict__ list,
                                                  const float* __restrict__ inv,
                                                  unsigned short* __restrict__ dst,
                                                  int base, int n) {
    constexpr int TPN = C / 8;           // lanes per node (8 or 16)
    constexpr int NPB = 256 / TPN;
    const int node = blockIdx.x * NPB + threadIdx.x / TPN;
    if (node >= n) return;
    const int c8 = (threadIdx.x % TPN) * 8;
    const int g = base + node;
    const int s = rp[g], e = rp[g + 1];

    float a[8];
#pragma unroll
    for (int j = 0; j < 8; ++j) a[j] = 0.f;

    int i = s;
    for (; i + 1 < e; i += 2) {
        int r0 = list[i], r1 = list[i + 1];
        short8 v0 = *reinterpret_cast<const short8*>(src + (size_t)r0 * C + c8);
        short8 v1 = *reinterpret_cast<const short8*>(src + (size_t)r1 * C + c8);
#pragma unroll
        for (int j = 0; j < 8; ++j)
            a[j] += b2f((unsigned short)v0[j]) + b2f((unsigned short)v1[j]);
    }
    if (i < e) {
        int r0 = list[i];
        short8 v0 = *reinterpret_cast<const short8*>(src + (size_t)r0 * C + c8);
#pragma unroll
        for (int j = 0; j < 8; ++j) a[j] += b2f((unsigned short)v0[j]);
    }
    const float sc = inv[g];
    short8 o;
#pragma unroll
    for (int j = 0; j < 8; ++j) o[j] = (short)f2b(a[j] * sc);
    *reinterpret_cast<short8*>(dst + (size_t)node * C + c8) = o;
}

// ---------------- MFMA bf16 GEMM: Y = [relu]( A @ W^T + vec + carry ) ----------------
// A: [M][K] bf16, W: [N][K] bf16, Y: [M][N] (bf16 or f32), vec: [N] f32, carry: [M][N] f32
// Block = 256 thr = 4 waves; tile 128 rows; wave = 32 rows x N cols.
// Frags (mfma_f32_16x16x32_bf16): A/B lane&15 = non-K index, k = (lane>>4)*8+j;
// D: col = lane&15, row = (lane>>4)*4 + reg   [verified layout, learn_hip m89/m91]
template<int K, int N, bool AVEC, bool CARRY, bool RELU, bool B16OUT>
__global__ __launch_bounds__(256) void k_mf(const unsigned short* __restrict__ A,
                                            const unsigned short* __restrict__ W,
                                            const float* __restrict__ vec,
                                            const float* __restrict__ carry,
                                            void* __restrict__ Yv, int M) {
    static_assert(K % 32 == 0 && N % 16 == 0, "shape");
    constexpr int KT = K / 32;
    constexpr int CG = N / 16;
    const int lane = threadIdx.x & 63;
    const int w = threadIdx.x >> 6;
    const int rbase = blockIdx.x * 128 + w * 32;
    const int lr = lane & 15;
    const int kg = lane >> 4;

    short8 a[2][KT];
#pragma unroll
    for (int t = 0; t < 2; ++t)
#pragma unroll
        for (int kt = 0; kt < KT; ++kt)
            a[t][kt] = *reinterpret_cast<const short8*>(
                A + (size_t)(rbase + t * 16 + lr) * K + kt * 32 + kg * 8);

    f32x4 acc[2][CG];
#pragma unroll
    for (int t = 0; t < 2; ++t)
#pragma unroll
        for (int c = 0; c < CG; ++c) acc[t][c] = (f32x4){0.f, 0.f, 0.f, 0.f};

#pragma unroll
    for (int cg = 0; cg < CG; ++cg) {
        short8 b[KT];
#pragma unroll
        for (int kt = 0; kt < KT; ++kt)
            b[kt] = *reinterpret_cast<const short8*>(
                W + (size_t)(cg * 16 + lr) * K + kt * 32 + kg * 8);
#pragma unroll
        for (int kt = 0; kt < KT; ++kt)
#pragma unroll
            for (int t = 0; t < 2; ++t)
                acc[t][cg] = __builtin_amdgcn_mfma_f32_16x16x32_bf16(
                    a[t][kt], b[kt], acc[t][cg], 0, 0, 0);
    }

#pragma unroll
    for (int t = 0; t < 2; ++t)
#pragma unroll
        for (int cg = 0; cg < CG; ++cg) {
            const int col = cg * 16 + lr;
            float vb = 0.f;
            if (AVEC) vb = vec[col];
#pragma unroll
            for (int r = 0; r < 4; ++r) {
                int row = rbase + t * 16 + kg * 4 + r;
                if (row < M) {
                    float v = acc[t][cg][r] + vb;
                    if (CARRY) v += carry[(size_t)row * N + col];
                    if (RELU) v = fmaxf(v, 0.f);
                    if (B16OUT)
                        ((unsigned short*)Yv)[(size_t)row * N + col] = f2b(v);
                    else
                        ((float*)Yv)[(size_t)row * N + col] = v;
                }
            }
        }
}

// ---------------- new_index output ----------------
__global__ void k_index(const int* __restrict__ t, float* __restrict__ o, int n, int nu) {
    int i = blockIdx.x * blockDim.x + threadIdx.x;
    if (i < n) {
        o[i] = (float)t[i];
        o[n + i] = (float)(t[n + i] + nu);
    }
}

extern "C" void kernel_launch(void* const* d_in, const int* in_sizes, int n_in,
                              void* d_out, int out_size, void* d_ws, size_t ws_size,
                              hipStream_t stream) {
    const float* movie_x  = (const float*)d_in[0];
    const int*   user_idx = (const int*)d_in[1];
    const int*   movie_idx= (const int*)d_in[2];
    const int*   tuples   = (const int*)d_in[3];
    const float* user_emb = (const float*)d_in[4];
    const float* W1l = (const float*)d_in[5];
    const float* b1  = (const float*)d_in[6];
    const float* W1r = (const float*)d_in[7];
    const float* W2l = (const float*)d_in[8];
    const float* b2  = (const float*)d_in[9];
    const float* W2r = (const float*)d_in[10];
    const float* W3l = (const float*)d_in[11];
    const float* b3  = (const float*)d_in[12];
    const float* W3r = (const float*)d_in[13];
    const float* Wlin1 = (const float*)d_in[14];
    const float* blin1 = (const float*)d_in[15];
    const float* Wlin2 = (const float*)d_in[16];
    const float* blin2 = (const float*)d_in[17];

    float* out = (float*)d_out;

    // ---- workspace layout (bytes) ----
    char* p = (char*)d_ws;
    int* icnt = (int*)p;  p += (size_t)NTOT * 4;
    int* cur  = (int*)p;  p += (size_t)NTOT * 4;
    int* rp   = (int*)p;  p += (size_t)(NTOT + 64) * 4;
    int* bsum = (int*)p;  p += 128 * 4;
    int* list = (int*)p;  p += (size_t)NLIST * 4;
    float* c1  = (float*)p; p += 128 * 4;
    float* inv = (float*)p; p += (size_t)NTOT * 4;
    unsigned short* wb = (unsigned short*)p; p += (size_t)CVT_TOT * 2;
    unsigned short* W1l_b  = wb;
    unsigned short* W2l_b  = wb + 8192;
    unsigned short* W2r_b  = wb + 24576;
    unsigned short* W3l_b  = wb + 32768;
    unsigned short* W3r_b  = wb + 49152;
    unsigned short* Wlin1_b= wb + 65536;
    unsigned short* Wlin2_b= wb + 73728;
    unsigned short* mxb    = wb + 81920;          // [NM][64] bf16
    // pool: mean1 | mean2 | Eb  (user_z aliases pool start later)
    unsigned short* pool = (unsigned short*)p;
    unsigned short* mean1 = pool;                                   // [NU][64] bf16
    unsigned short* mean2 = pool + (size_t)NU * FEAT;               // [NM][128] bf16
    float* Eb = (float*)(pool + (size_t)NU * FEAT + (size_t)NM * HID); // [NM][128] f32
    unsigned short* user_z = pool;                                  // alias, [NU][128] bf16
    p += (size_t)NU * FEAT * 2 + (size_t)NM * HID * 2 + (size_t)NM * HID * 4;
    unsigned short* user_x = (unsigned short*)p; p += (size_t)NU * HID * 2;  // [NU][128]
    unsigned short* mean3 = user_x;                                 // alias (after G3a)
    unsigned short* movie_z = (unsigned short*)p; p += (size_t)NM * HID * 2; // [NM][128]
    float* Cb = (float*)p; p += (size_t)NU * HID * 4;               // t3 [NU][128] f32

    const int NBLK = (NTOT + 1023) / 1024;

    // ---- build CSR ----
    hipMemsetAsync(icnt, 0, (size_t)NTOT * 2 * sizeof(int), stream);
    k_count_i<<<(NE + 255) / 256, 256, 0, stream>>>(user_idx, movie_idx, icnt, NE);
    k_scan1<<<NBLK, 256, 0, stream>>>(icnt, rp, bsum, NTOT);
    k_scan2<<<1, 128, 0, stream>>>(bsum, rp, NBLK, NTOT);
    k_scan3<<<NBLK, 256, 0, stream>>>(rp, bsum, NTOT);
    k_inv_f<<<(NTOT + 255) / 256, 256, 0, stream>>>(icnt, inv, NTOT);
    k_fill<<<(NE + 255) / 256, 256, 0, stream>>>(user_idx, movie_idx, rp, cur, list, NE);

    // ---- dtype conversions + c1 ----
    k_cvt<<<(CVT_TOT + 255) / 256, 256, 0, stream>>>(W1l, W2l, W2r, W3l, W3r,
                                                     Wlin1, Wlin2, movie_x, wb);
    k_c1<<<1, 128, 0, stream>>>(user_emb, W1r, b1, c1);

    // ---- conv1 ----
    k_gather_b<FEAT><<<(NU + 31) / 32, 256, 0, stream>>>(mxb, rp, list, inv, mean1, 0, NU);
    k_mf<FEAT, HID, true, false, true, true><<<(NU + 127) / 128, 256, 0, stream>>>(
        mean1, W1l_b, c1, nullptr, user_x, NU);

    // ---- conv2 ----
    k_gather_b<HID><<<(NM + 15) / 16, 256, 0, stream>>>(user_x, rp, list, inv, mean2, NU, NM);
    k_mf<FEAT, HID, true, false, false, false><<<(NM + 127) / 128, 256, 0, stream>>>(
        mxb, W2r_b, b2, nullptr, Eb, NM);
    k_mf<HID, HID, false, true, true, true><<<(NM + 127) / 128, 256, 0, stream>>>(
        mean2, W2l_b, nullptr, Eb, movie_z, NM);
    k_mf<HID, OUTD, true, false, false, false><<<(NM + 127) / 128, 256, 0, stream>>>(
        movie_z, Wlin2_b, blin2, nullptr, out + (size_t)NU * OUTD, NM);

    // ---- conv3 (t3 first: consumes user_x before mean3 aliases it) ----
    k_mf<HID, HID, true, false, false, false><<<(NU + 127) / 128, 256, 0, stream>>>(
        user_x, W3r_b, b3, nullptr, Cb, NU);
    k_gather_b<HID><<<(NU + 15) / 16, 256, 0, stream>>>(movie_z, rp, list, inv, mean3, 0, NU);
    k_mf<HID, HID, false, true, true, true><<<(NU + 127) / 128, 256, 0, stream>>>(
        mean3, W3l_b, nullptr, Cb, user_z, NU);
    k_mf<HID, OUTD, true, false, false, false><<<(NU + 127) / 128, 256, 0, stream>>>(
        user_z, Wlin1_b, blin1, nullptr, out, NU);

    // ---- new_index ----
    k_index<<<(100000 + 255) / 256, 256, 0, stream>>>(
        tuples, out + (size_t)(NU + NM) * OUTD, 100000, NU);
}

// Round 5
// 271.044 us; speedup vs baseline: 20.5752x; 1.3447x over previous
//
#include <hip/hip_runtime.h>

typedef __attribute__((ext_vector_type(8))) short short8;   // 8 bf16 (4 VGPR)
typedef __attribute__((ext_vector_type(4))) float f32x4;    // MFMA acc

static const int NU = 100000;
static const int NM = 20000;
static const int NE = 600000;
static const int FEAT = 64;
static const int HID = 128;
static const int OUTD = 64;
static const int NTOT = NU + NM;
static const int NLIST = 2 * NE;
static const int CVT_TOT = 81920 + NM * FEAT;   // weights + movie_x

// bucket geometry: users 512 nodes/bucket, movies 128 nodes/bucket (~3.1-3.8k edges each)
static const int UB_SHIFT = 9;                    // 512
static const int MB_SHIFT = 7;                    // 128
static const int NBU = (NU + 511) >> 9;           // 196
static const int NBM = (NM + 127) >> 7;           // 157
static const int NBUCK = NBU + NBM;               // 353
static const int EPB = 4096;                      // edges per partition block
static const int NPBLK = (NE + EPB - 1) / EPB;    // 147

__device__ inline float b2f(unsigned short h) {
    unsigned int u = ((unsigned int)h) << 16;
    float f; __builtin_memcpy(&f, &u, 4); return f;
}
__device__ inline unsigned short f2b(float f) {
    unsigned int u; __builtin_memcpy(&u, &f, 4);
    u += 0x7FFFu + ((u >> 16) & 1u);            // RNE
    return (unsigned short)(u >> 16);
}

// ---------------- pass 1: bucket histogram (LDS-aggregated) ----------------
__global__ __launch_bounds__(256) void k_hist(const int* __restrict__ ui,
                                              const int* __restrict__ mi,
                                              int* __restrict__ ghist) {
    __shared__ int h[NBUCK];
    const int tid = threadIdx.x;
    for (int i = tid; i < NBUCK; i += 256) h[i] = 0;
    __syncthreads();
#pragma unroll
    for (int it = 0; it < EPB / 256; ++it) {
        int e = blockIdx.x * EPB + it * 256 + tid;
        if (e < NE) {
            atomicAdd(&h[ui[e] >> UB_SHIFT], 1);
            atomicAdd(&h[NBU + (mi[e] >> MB_SHIFT)], 1);
        }
    }
    __syncthreads();
    for (int i = tid; i < NBUCK; i += 256)
        if (h[i]) atomicAdd(&ghist[i], h[i]);
}

// ---------------- pass 2: scan bucket sizes -> bb[], init gcur[] ----------------
__global__ __launch_bounds__(512) void k_bscan(const int* __restrict__ ghist,
                                               int* __restrict__ bb,
                                               int* __restrict__ gcur) {
    __shared__ int s[512];
    const int tid = threadIdx.x;
    int v = (tid < NBUCK) ? ghist[tid] : 0;
    s[tid] = v;
    __syncthreads();
#pragma unroll
    for (int off = 1; off < 512; off <<= 1) {
        int x = (tid >= off) ? s[tid - off] : 0;
        __syncthreads();
        s[tid] += x;
        __syncthreads();
    }
    int excl = s[tid] - v;
    if (tid < NBUCK) { bb[tid] = excl; gcur[tid] = excl; }
    if (tid == 511) bb[NBUCK] = s[511];
}

// ---------------- pass 3: partition edges into bucket-contiguous entry runs ----------------
// entry payload: user bucket -> (m << 9) | (u & 511); movie bucket -> (u << 7) | (m & 127)
__global__ __launch_bounds__(256) void k_part(const int* __restrict__ ui,
                                              const int* __restrict__ mi,
                                              int* __restrict__ gcur,
                                              int* __restrict__ entries) {
    __shared__ int h[NBUCK], base[NBUCK], cur[NBUCK];
    const int tid = threadIdx.x;
    for (int i = tid; i < NBUCK; i += 256) h[i] = 0;
    __syncthreads();

    int eu[EPB / 256], em[EPB / 256];
#pragma unroll
    for (int it = 0; it < EPB / 256; ++it) {
        int e = blockIdx.x * EPB + it * 256 + tid;
        if (e < NE) {
            eu[it] = ui[e]; em[it] = mi[e];
            atomicAdd(&h[eu[it] >> UB_SHIFT], 1);
            atomicAdd(&h[NBU + (em[it] >> MB_SHIFT)], 1);
        } else eu[it] = -1;
    }
    __syncthreads();
    for (int i = tid; i < NBUCK; i += 256) {
        int c = h[i];
        base[i] = c ? atomicAdd(&gcur[i], c) : 0;
        cur[i] = 0;
    }
    __syncthreads();
#pragma unroll
    for (int it = 0; it < EPB / 256; ++it) {
        if (eu[it] < 0) continue;
        int u = eu[it], m = em[it];
        int bu = u >> UB_SHIFT;
        int o1 = base[bu] + atomicAdd(&cur[bu], 1);
        entries[o1] = (m << UB_SHIFT) | (u & 511);
        int bm = NBU + (m >> MB_SHIFT);
        int o2 = base[bm] + atomicAdd(&cur[bm], 1);
        entries[o2] = (u << MB_SHIFT) | (m & 127);
    }
}

// ---------------- pass 4: per-bucket CSR build in LDS ----------------
__global__ __launch_bounds__(256) void k_csr(const int* __restrict__ bb,
                                             const int* __restrict__ entries,
                                             int* __restrict__ rp,
                                             int* __restrict__ list) {
    __shared__ int lcnt[512], lrp[512], lcur[512], ps[256];
    const int b = blockIdx.x;
    const int tid = threadIdx.x;
    const int s = bb[b], e = bb[b + 1];
    const bool isU = b < NBU;
    const int shift = isU ? UB_SHIFT : MB_SHIFT;
    const int mask = isU ? 511 : 127;
    const int n0 = isU ? (b << UB_SHIFT) : ((b - NBU) << MB_SHIFT);
    const int nNodes = isU ? min(512, NU - n0) : min(128, NM - n0);
    const int g0 = isU ? n0 : NU + n0;

    for (int i = tid; i < 512; i += 256) { lcnt[i] = 0; lcur[i] = 0; }
    __syncthreads();
    for (int i = s + tid; i < e; i += 256)
        atomicAdd(&lcnt[entries[i] & mask], 1);
    __syncthreads();
    // exclusive scan over 512 via 256 threads x 2
    int a0 = lcnt[2 * tid], a1 = lcnt[2 * tid + 1];
    int pr = a0 + a1;
    ps[tid] = pr;
    __syncthreads();
#pragma unroll
    for (int off = 1; off < 256; off <<= 1) {
        int x = (tid >= off) ? ps[tid - off] : 0;
        __syncthreads();
        ps[tid] += x;
        __syncthreads();
    }
    int excl = ps[tid] - pr;
    lrp[2 * tid] = excl;
    lrp[2 * tid + 1] = excl + a0;
    __syncthreads();
    for (int i = tid; i < nNodes; i += 256) rp[g0 + i] = s + lrp[i];
    if (b == NBUCK - 1 && tid == 0) rp[NTOT] = e;
    for (int i = s + tid; i < e; i += 256) {
        int p = entries[i];
        int dl = p & mask;
        int off = s + lrp[dl] + atomicAdd(&lcur[dl], 1);
        list[off] = p >> shift;
    }
}

// ---------------- fp32 -> bf16 conversion (weights + movie_x) ----------------
__global__ void k_cvt(const float* __restrict__ w1l, const float* __restrict__ w2l,
                      const float* __restrict__ w2r, const float* __restrict__ w3l,
                      const float* __restrict__ w3r, const float* __restrict__ wl1,
                      const float* __restrict__ wl2, const float* __restrict__ mx,
                      unsigned short* __restrict__ dst) {
    int g = blockIdx.x * blockDim.x + threadIdx.x;
    if (g >= CVT_TOT) return;
    const float* s; int o;
    if      (g < 8192)   { s = w1l; o = g; }
    else if (g < 24576)  { s = w2l; o = g - 8192; }
    else if (g < 32768)  { s = w2r; o = g - 24576; }
    else if (g < 49152)  { s = w3l; o = g - 32768; }
    else if (g < 65536)  { s = w3r; o = g - 49152; }
    else if (g < 73728)  { s = wl1; o = g - 65536; }
    else if (g < 81920)  { s = wl2; o = g - 73728; }
    else                 { s = mx;  o = g - 81920; }
    dst[g] = f2b(s[o]);
}

// ---------------- c1 = b1 + user_emb @ W1r^T ----------------
__global__ void k_c1(const float* __restrict__ ue, const float* __restrict__ w1r,
                     const float* __restrict__ b1, float* __restrict__ c1) {
    int h = threadIdx.x;
    float a = 0.f;
#pragma unroll 16
    for (int k = 0; k < HID; ++k) a += ue[k] * w1r[h * HID + k];
    c1[h] = a + b1[h];
}

// ---------------- bf16 gather-based segment mean (degree from rp) ----------------
template<int C>
__global__ __launch_bounds__(256) void k_gather_b(const unsigned short* __restrict__ src,
                                                  const int* __restrict__ rp,
                                                  const int* __restrict__ list,
                                                  unsigned short* __restrict__ dst,
                                                  int base, int n) {
    constexpr int TPN = C / 8;
    constexpr int NPB = 256 / TPN;
    const int node = blockIdx.x * NPB + threadIdx.x / TPN;
    if (node >= n) return;
    const int c8 = (threadIdx.x % TPN) * 8;
    const int g = base + node;
    const int s = rp[g], e = rp[g + 1];

    float a[8];
#pragma unroll
    for (int j = 0; j < 8; ++j) a[j] = 0.f;

    int i = s;
    for (; i + 1 < e; i += 2) {
        int r0 = list[i], r1 = list[i + 1];
        short8 v0 = *reinterpret_cast<const short8*>(src + (size_t)r0 * C + c8);
        short8 v1 = *reinterpret_cast<const short8*>(src + (size_t)r1 * C + c8);
#pragma unroll
        for (int j = 0; j < 8; ++j)
            a[j] += b2f((unsigned short)v0[j]) + b2f((unsigned short)v1[j]);
    }
    if (i < e) {
        int r0 = list[i];
        short8 v0 = *reinterpret_cast<const short8*>(src + (size_t)r0 * C + c8);
#pragma unroll
        for (int j = 0; j < 8; ++j) a[j] += b2f((unsigned short)v0[j]);
    }
    const float sc = 1.0f / (float)max(e - s, 1);
    short8 o;
#pragma unroll
    for (int j = 0; j < 8; ++j) o[j] = (short)f2b(a[j] * sc);
    *reinterpret_cast<short8*>(dst + (size_t)node * C + c8) = o;
}

// ---------------- MFMA bf16 GEMM: Y = [relu]( A @ W^T + vec + carry ) ----------------
// carry dtype selected by CB16 (bf16) else f32.
template<int K, int N, bool AVEC, bool CARRY, bool RELU, bool B16OUT, bool CB16>
__global__ __launch_bounds__(256) void k_mf(const unsigned short* __restrict__ A,
                                            const unsigned short* __restrict__ W,
                                            const float* __restrict__ vec,
                                            const void* __restrict__ carry,
                                            void* __restrict__ Yv, int M) {
    static_assert(K % 32 == 0 && N % 16 == 0, "shape");
    constexpr int KT = K / 32;
    constexpr int CG = N / 16;
    const int lane = threadIdx.x & 63;
    const int w = threadIdx.x >> 6;
    const int rbase = blockIdx.x * 128 + w * 32;
    const int lr = lane & 15;
    const int kg = lane >> 4;

    short8 a[2][KT];
#pragma unroll
    for (int t = 0; t < 2; ++t)
#pragma unroll
        for (int kt = 0; kt < KT; ++kt)
            a[t][kt] = *reinterpret_cast<const short8*>(
                A + (size_t)(rbase + t * 16 + lr) * K + kt * 32 + kg * 8);

    f32x4 acc[2][CG];
#pragma unroll
    for (int t = 0; t < 2; ++t)
#pragma unroll
        for (int c = 0; c < CG; ++c) acc[t][c] = (f32x4){0.f, 0.f, 0.f, 0.f};

#pragma unroll
    for (int cg = 0; cg < CG; ++cg) {
        short8 b[KT];
#pragma unroll
        for (int kt = 0; kt < KT; ++kt)
            b[kt] = *reinterpret_cast<const short8*>(
                W + (size_t)(cg * 16 + lr) * K + kt * 32 + kg * 8);
#pragma unroll
        for (int kt = 0; kt < KT; ++kt)
#pragma unroll
            for (int t = 0; t < 2; ++t)
                acc[t][cg] = __builtin_amdgcn_mfma_f32_16x16x32_bf16(
                    a[t][kt], b[kt], acc[t][cg], 0, 0, 0);
    }

#pragma unroll
    for (int t = 0; t < 2; ++t)
#pragma unroll
        for (int cg = 0; cg < CG; ++cg) {
            const int col = cg * 16 + lr;
            float vb = 0.f;
            if (AVEC) vb = vec[col];
#pragma unroll
            for (int r = 0; r < 4; ++r) {
                int row = rbase + t * 16 + kg * 4 + r;
                if (row < M) {
                    float v = acc[t][cg][r] + vb;
                    if (CARRY) {
                        if (CB16) v += b2f(((const unsigned short*)carry)[(size_t)row * N + col]);
                        else      v += ((const float*)carry)[(size_t)row * N + col];
                    }
                    if (RELU) v = fmaxf(v, 0.f);
                    if (B16OUT)
                        ((unsigned short*)Yv)[(size_t)row * N + col] = f2b(v);
                    else
                        ((float*)Yv)[(size_t)row * N + col] = v;
                }
            }
        }
}

// ---------------- new_index output ----------------
__global__ void k_index(const int* __restrict__ t, float* __restrict__ o, int n, int nu) {
    int i = blockIdx.x * blockDim.x + threadIdx.x;
    if (i < n) {
        o[i] = (float)t[i];
        o[n + i] = (float)(t[n + i] + nu);
    }
}

extern "C" void kernel_launch(void* const* d_in, const int* in_sizes, int n_in,
                              void* d_out, int out_size, void* d_ws, size_t ws_size,
                              hipStream_t stream) {
    const float* movie_x  = (const float*)d_in[0];
    const int*   user_idx = (const int*)d_in[1];
    const int*   movie_idx= (const int*)d_in[2];
    const int*   tuples   = (const int*)d_in[3];
    const float* user_emb = (const float*)d_in[4];
    const float* W1l = (const float*)d_in[5];
    const float* b1  = (const float*)d_in[6];
    const float* W1r = (const float*)d_in[7];
    const float* W2l = (const float*)d_in[8];
    const float* b2  = (const float*)d_in[9];
    const float* W2r = (const float*)d_in[10];
    const float* W3l = (const float*)d_in[11];
    const float* b3  = (const float*)d_in[12];
    const float* W3r = (const float*)d_in[13];
    const float* Wlin1 = (const float*)d_in[14];
    const float* blin1 = (const float*)d_in[15];
    const float* Wlin2 = (const float*)d_in[16];
    const float* blin2 = (const float*)d_in[17];

    float* out = (float*)d_out;

    // ---- workspace layout (bytes, all chunks 16B-aligned) ----
    char* p = (char*)d_ws;
    int* ghist = (int*)p;  p += 360 * 4;
    int* bb    = (int*)p;  p += 360 * 4;
    int* gcur  = (int*)p;  p += 360 * 4;
    int* entries = (int*)p; p += (size_t)NLIST * 4;
    int* rp    = (int*)p;  p += (size_t)(NTOT + 8) * 4;
    int* list  = (int*)p;  p += (size_t)NLIST * 4;
    float* c1  = (float*)p; p += 128 * 4;
    unsigned short* wb = (unsigned short*)p; p += (size_t)CVT_TOT * 2;
    unsigned short* W1l_b  = wb;
    unsigned short* W2l_b  = wb + 8192;
    unsigned short* W2r_b  = wb + 24576;
    unsigned short* W3l_b  = wb + 32768;
    unsigned short* W3r_b  = wb + 49152;
    unsigned short* Wlin1_b= wb + 65536;
    unsigned short* Wlin2_b= wb + 73728;
    unsigned short* mxb    = wb + 81920;                              // [NM][64]
    unsigned short* mean1  = (unsigned short*)p; p += (size_t)NU * FEAT * 2;
    unsigned short* user_x = (unsigned short*)p; p += (size_t)NU * HID * 2;
    unsigned short* mean2  = (unsigned short*)p; p += (size_t)NM * HID * 2;
    unsigned short* t2     = (unsigned short*)p; p += (size_t)NM * HID * 2;
    unsigned short* movie_z= (unsigned short*)p; p += (size_t)NM * HID * 2;
    unsigned short* t3     = (unsigned short*)p; p += (size_t)NU * HID * 2;
    unsigned short* user_z = (unsigned short*)p; p += (size_t)NU * HID * 2;
    unsigned short* mean3  = mean1;               // alias: mean1 dead after conv1 GEMM

    // ---- CSR build: hist -> scan -> partition -> per-bucket CSR ----
    hipMemsetAsync(ghist, 0, NBUCK * sizeof(int), stream);
    k_hist<<<NPBLK, 256, 0, stream>>>(user_idx, movie_idx, ghist);
    k_bscan<<<1, 512, 0, stream>>>(ghist, bb, gcur);
    k_part<<<NPBLK, 256, 0, stream>>>(user_idx, movie_idx, gcur, entries);
    k_csr<<<NBUCK, 256, 0, stream>>>(bb, entries, rp, list);

    // ---- dtype conversions + c1 ----
    k_cvt<<<(CVT_TOT + 255) / 256, 256, 0, stream>>>(W1l, W2l, W2r, W3l, W3r,
                                                     Wlin1, Wlin2, movie_x, wb);
    k_c1<<<1, 128, 0, stream>>>(user_emb, W1r, b1, c1);

    // ---- conv1 ----
    k_gather_b<FEAT><<<(NU + 31) / 32, 256, 0, stream>>>(mxb, rp, list, mean1, 0, NU);
    k_mf<FEAT, HID, true, false, true, true, false><<<(NU + 127) / 128, 256, 0, stream>>>(
        mean1, W1l_b, c1, nullptr, user_x, NU);

    // ---- conv2 ----
    k_gather_b<HID><<<(NM + 15) / 16, 256, 0, stream>>>(user_x, rp, list, mean2, NU, NM);
    k_mf<FEAT, HID, true, false, false, true, false><<<(NM + 127) / 128, 256, 0, stream>>>(
        mxb, W2r_b, b2, nullptr, t2, NM);
    k_mf<HID, HID, false, true, true, true, true><<<(NM + 127) / 128, 256, 0, stream>>>(
        mean2, W2l_b, nullptr, t2, movie_z, NM);
    k_mf<HID, OUTD, true, false, false, false, false><<<(NM + 127) / 128, 256, 0, stream>>>(
        movie_z, Wlin2_b, blin2, nullptr, out + (size_t)NU * OUTD, NM);

    // ---- conv3 (t3 consumes user_x before mean3 aliases mean1) ----
    k_mf<HID, HID, true, false, false, true, false><<<(NU + 127) / 128, 256, 0, stream>>>(
        user_x, W3r_b, b3, nullptr, t3, NU);
    k_gather_b<HID><<<(NU + 15) / 16, 256, 0, stream>>>(movie_z, rp, list, mean3, 0, NU);
    k_mf<HID, HID, false, true, true, true, true><<<(NU + 127) / 128, 256, 0, stream>>>(
        mean3, W3l_b, nullptr, t3, user_z, NU);
    k_mf<HID, OUTD, true, false, false, false, false><<<(NU + 127) / 128, 256, 0, stream>>>(
        user_z, Wlin1_b, blin1, nullptr, out, NU);

    // ---- new_index ----
    k_index<<<(100000 + 255) / 256, 256, 0, stream>>>(
        tuples, out + (size_t)(NU + NM) * OUTD, 100000, NU);
}

// Round 6
// 214.176 us; speedup vs baseline: 26.0382x; 1.2655x over previous
//
#include <hip/hip_runtime.h>

typedef __attribute__((ext_vector_type(8))) short short8;   // 8 bf16 (4 VGPR)
typedef __attribute__((ext_vector_type(4))) float f32x4;    // MFMA acc

static const int NU = 100000;
static const int NM = 20000;
static const int NE = 600000;
static const int FEAT = 64;
static const int HID = 128;
static const int OUTD = 64;
static const int NTOT = NU + NM;
static const int NLIST = 2 * NE;
static const int CVT_TOT = 81920 + NM * FEAT;   // weights + movie_x

// bucket geometry: users 512 nodes/bucket, movies 128 nodes/bucket
static const int UB_SHIFT = 9;
static const int MB_SHIFT = 7;
static const int NBU = (NU + 511) >> 9;           // 196
static const int NBM = (NM + 127) >> 7;           // 157
static const int NBUCK = NBU + NBM;               // 353
static const int EPB = 4096;
static const int NPBLK = (NE + EPB - 1) / EPB;    // 147

__device__ inline float b2f(unsigned short h) {
    unsigned int u = ((unsigned int)h) << 16;
    float f; __builtin_memcpy(&f, &u, 4); return f;
}
__device__ inline unsigned short f2b(float f) {
    unsigned int u; __builtin_memcpy(&u, &f, 4);
    u += 0x7FFFu + ((u >> 16) & 1u);            // RNE
    return (unsigned short)(u >> 16);
}
__device__ inline unsigned int pk2(float a, float b) {
    return (unsigned int)f2b(a) | ((unsigned int)f2b(b) << 16);
}

// ---------------- CSR build (hist -> scan -> partition -> per-bucket CSR) ----------------
__global__ __launch_bounds__(256) void k_hist(const int* __restrict__ ui,
                                              const int* __restrict__ mi,
                                              int* __restrict__ ghist) {
    __shared__ int h[NBUCK];
    const int tid = threadIdx.x;
    for (int i = tid; i < NBUCK; i += 256) h[i] = 0;
    __syncthreads();
#pragma unroll
    for (int it = 0; it < EPB / 256; ++it) {
        int e = blockIdx.x * EPB + it * 256 + tid;
        if (e < NE) {
            atomicAdd(&h[ui[e] >> UB_SHIFT], 1);
            atomicAdd(&h[NBU + (mi[e] >> MB_SHIFT)], 1);
        }
    }
    __syncthreads();
    for (int i = tid; i < NBUCK; i += 256)
        if (h[i]) atomicAdd(&ghist[i], h[i]);
}

__global__ __launch_bounds__(512) void k_bscan(const int* __restrict__ ghist,
                                               int* __restrict__ bb,
                                               int* __restrict__ gcur) {
    __shared__ int s[512];
    const int tid = threadIdx.x;
    int v = (tid < NBUCK) ? ghist[tid] : 0;
    s[tid] = v;
    __syncthreads();
#pragma unroll
    for (int off = 1; off < 512; off <<= 1) {
        int x = (tid >= off) ? s[tid - off] : 0;
        __syncthreads();
        s[tid] += x;
        __syncthreads();
    }
    int excl = s[tid] - v;
    if (tid < NBUCK) { bb[tid] = excl; gcur[tid] = excl; }
    if (tid == 511) bb[NBUCK] = s[511];
}

__global__ __launch_bounds__(256) void k_part(const int* __restrict__ ui,
                                              const int* __restrict__ mi,
                                              int* __restrict__ gcur,
                                              int* __restrict__ entries) {
    __shared__ int h[NBUCK], base[NBUCK], cur[NBUCK];
    const int tid = threadIdx.x;
    for (int i = tid; i < NBUCK; i += 256) h[i] = 0;
    __syncthreads();

    int eu[EPB / 256], em[EPB / 256];
#pragma unroll
    for (int it = 0; it < EPB / 256; ++it) {
        int e = blockIdx.x * EPB + it * 256 + tid;
        if (e < NE) {
            eu[it] = ui[e]; em[it] = mi[e];
            atomicAdd(&h[eu[it] >> UB_SHIFT], 1);
            atomicAdd(&h[NBU + (em[it] >> MB_SHIFT)], 1);
        } else eu[it] = -1;
    }
    __syncthreads();
    for (int i = tid; i < NBUCK; i += 256) {
        int c = h[i];
        base[i] = c ? atomicAdd(&gcur[i], c) : 0;
        cur[i] = 0;
    }
    __syncthreads();
#pragma unroll
    for (int it = 0; it < EPB / 256; ++it) {
        if (eu[it] < 0) continue;
        int u = eu[it], m = em[it];
        int bu = u >> UB_SHIFT;
        int o1 = base[bu] + atomicAdd(&cur[bu], 1);
        entries[o1] = (m << UB_SHIFT) | (u & 511);
        int bm = NBU + (m >> MB_SHIFT);
        int o2 = base[bm] + atomicAdd(&cur[bm], 1);
        entries[o2] = (u << MB_SHIFT) | (m & 127);
    }
}

__global__ __launch_bounds__(256) void k_csr(const int* __restrict__ bb,
                                             const int* __restrict__ entries,
                                             int* __restrict__ rp,
                                             int* __restrict__ list) {
    __shared__ int lcnt[512], lrp[512], lcur[512], ps[256];
    const int b = blockIdx.x;
    const int tid = threadIdx.x;
    const int s = bb[b], e = bb[b + 1];
    const bool isU = b < NBU;
    const int shift = isU ? UB_SHIFT : MB_SHIFT;
    const int mask = isU ? 511 : 127;
    const int n0 = isU ? (b << UB_SHIFT) : ((b - NBU) << MB_SHIFT);
    const int nNodes = isU ? min(512, NU - n0) : min(128, NM - n0);
    const int g0 = isU ? n0 : NU + n0;

    for (int i = tid; i < 512; i += 256) { lcnt[i] = 0; lcur[i] = 0; }
    __syncthreads();
    for (int i = s + tid; i < e; i += 256)
        atomicAdd(&lcnt[entries[i] & mask], 1);
    __syncthreads();
    int a0 = lcnt[2 * tid], a1 = lcnt[2 * tid + 1];
    int pr = a0 + a1;
    ps[tid] = pr;
    __syncthreads();
#pragma unroll
    for (int off = 1; off < 256; off <<= 1) {
        int x = (tid >= off) ? ps[tid - off] : 0;
        __syncthreads();
        ps[tid] += x;
        __syncthreads();
    }
    int excl = ps[tid] - pr;
    lrp[2 * tid] = excl;
    lrp[2 * tid + 1] = excl + a0;
    __syncthreads();
    for (int i = tid; i < nNodes; i += 256) rp[g0 + i] = s + lrp[i];
    if (b == NBUCK - 1 && tid == 0) rp[NTOT] = e;
    for (int i = s + tid; i < e; i += 256) {
        int p = entries[i];
        int dl = p & mask;
        int off = s + lrp[dl] + atomicAdd(&lcur[dl], 1);
        list[off] = p >> shift;
    }
}

// ---------------- fp32 -> bf16 conversion (weights + movie_x) ----------------
__global__ void k_cvt(const float* __restrict__ w1l, const float* __restrict__ w2l,
                      const float* __restrict__ w2r, const float* __restrict__ w3l,
                      const float* __restrict__ w3r, const float* __restrict__ wl1,
                      const float* __restrict__ wl2, const float* __restrict__ mx,
                      unsigned short* __restrict__ dst) {
    int g = blockIdx.x * blockDim.x + threadIdx.x;
    if (g >= CVT_TOT) return;
    const float* s; int o;
    if      (g < 8192)   { s = w1l; o = g; }
    else if (g < 24576)  { s = w2l; o = g - 8192; }
    else if (g < 32768)  { s = w2r; o = g - 24576; }
    else if (g < 49152)  { s = w3l; o = g - 32768; }
    else if (g < 65536)  { s = w3r; o = g - 49152; }
    else if (g < 73728)  { s = wl1; o = g - 65536; }
    else if (g < 81920)  { s = wl2; o = g - 73728; }
    else                 { s = mx;  o = g - 81920; }
    dst[g] = f2b(s[o]);
}

// ---------------- c1 = b1 + user_emb @ W1r^T ----------------
__global__ void k_c1(const float* __restrict__ ue, const float* __restrict__ w1r,
                     const float* __restrict__ b1, float* __restrict__ c1) {
    int h = threadIdx.x;
    float a = 0.f;
#pragma unroll 16
    for (int k = 0; k < HID; ++k) a += ue[k] * w1r[h * HID + k];
    c1[h] = a + b1[h];
}

// ---------------- bf16 gather-based segment mean ----------------
template<int C>
__global__ __launch_bounds__(256) void k_gather_b(const unsigned short* __restrict__ src,
                                                  const int* __restrict__ rp,
                                                  const int* __restrict__ list,
                                                  unsigned short* __restrict__ dst,
                                                  int base, int n) {
    constexpr int TPN = C / 8;
    constexpr int NPB = 256 / TPN;
    const int node = blockIdx.x * NPB + threadIdx.x / TPN;
    if (node >= n) return;
    const int c8 = (threadIdx.x % TPN) * 8;
    const int g = base + node;
    const int s = rp[g], e = rp[g + 1];

    float a[8];
#pragma unroll
    for (int j = 0; j < 8; ++j) a[j] = 0.f;

    int i = s;
    for (; i + 1 < e; i += 2) {
        int r0 = list[i], r1 = list[i + 1];
        short8 v0 = *reinterpret_cast<const short8*>(src + (size_t)r0 * C + c8);
        short8 v1 = *reinterpret_cast<const short8*>(src + (size_t)r1 * C + c8);
#pragma unroll
        for (int j = 0; j < 8; ++j)
            a[j] += b2f((unsigned short)v0[j]) + b2f((unsigned short)v1[j]);
    }
    if (i < e) {
        int r0 = list[i];
        short8 v0 = *reinterpret_cast<const short8*>(src + (size_t)r0 * C + c8);
#pragma unroll
        for (int j = 0; j < 8; ++j) a[j] += b2f((unsigned short)v0[j]);
    }
    const float sc = 1.0f / (float)max(e - s, 1);
    short8 o;
#pragma unroll
    for (int j = 0; j < 8; ++j) o[j] = (short)f2b(a[j] * sc);
    *reinterpret_cast<short8*>(dst + (size_t)node * C + c8) = o;
}

// ================= swapped-operand MFMA GEMM =================
// Y[u][h] = [relu]( X[u][:] @ W[h][:]^T + vec[h] )
// mfma(A=W_frag, B=X_frag): D.col(lane&15) = u (X row), D.row = h, 4 CONTIGUOUS h per reg
// quad -> packed dwordx2 (bf16) / dwordx4 (f32) stores.
template<int K, int NO, bool AVEC, bool RELU, bool F32OUT>
__global__ __launch_bounds__(256) void k_mf2(const unsigned short* __restrict__ X,
                                             const unsigned short* __restrict__ W,
                                             const float* __restrict__ vec,
                                             void* __restrict__ Yv, int M) {
    constexpr int KT = K / 32;
    constexpr int CG = NO / 16;
    const int lane = threadIdx.x & 63;
    const int wv = threadIdx.x >> 6;
    const int rbase = blockIdx.x * 128 + wv * 32;
    const int lr = lane & 15;
    const int kg = lane >> 4;

    short8 xb[2][KT];
#pragma unroll
    for (int t = 0; t < 2; ++t) {
        int row = min(rbase + t * 16 + lr, M - 1);
#pragma unroll
        for (int kt = 0; kt < KT; ++kt)
            xb[t][kt] = *reinterpret_cast<const short8*>(
                X + (size_t)row * K + kt * 32 + kg * 8);
    }

    f32x4 acc[2][CG];
#pragma unroll
    for (int t = 0; t < 2; ++t)
#pragma unroll
        for (int c = 0; c < CG; ++c) acc[t][c] = (f32x4){0.f, 0.f, 0.f, 0.f};

#pragma unroll
    for (int cg = 0; cg < CG; ++cg) {
        short8 wf[KT];
#pragma unroll
        for (int kt = 0; kt < KT; ++kt)
            wf[kt] = *reinterpret_cast<const short8*>(
                W + (size_t)(cg * 16 + lr) * K + kt * 32 + kg * 8);
#pragma unroll
        for (int kt = 0; kt < KT; ++kt)
#pragma unroll
            for (int t = 0; t < 2; ++t)
                acc[t][cg] = __builtin_amdgcn_mfma_f32_16x16x32_bf16(
                    wf[kt], xb[t][kt], acc[t][cg], 0, 0, 0);
    }

#pragma unroll
    for (int t = 0; t < 2; ++t) {
        const int u = rbase + t * 16 + lr;
        if (u >= M) continue;
#pragma unroll
        for (int cg = 0; cg < CG; ++cg) {
            const int h0 = cg * 16 + kg * 4;
            float v[4];
#pragma unroll
            for (int r = 0; r < 4; ++r) v[r] = acc[t][cg][r];
            if (AVEC) {
                float4 vv = *reinterpret_cast<const float4*>(vec + h0);
                v[0] += vv.x; v[1] += vv.y; v[2] += vv.z; v[3] += vv.w;
            }
            if (RELU)
#pragma unroll
                for (int r = 0; r < 4; ++r) v[r] = fmaxf(v[r], 0.f);
            if (F32OUT) {
                float4 o = make_float4(v[0], v[1], v[2], v[3]);
                *reinterpret_cast<float4*>((float*)Yv + (size_t)u * NO + h0) = o;
            } else {
                uint2 o = make_uint2(pk2(v[0], v[1]), pk2(v[2], v[3]));
                *reinterpret_cast<uint2*>((unsigned short*)Yv + (size_t)u * NO + h0) = o;
            }
        }
    }
}

// LDS swizzled Z-tile helpers: byte ^= ((row&7)<<4)
__device__ inline int zswz(int row, int bcol) { return row * 256 + (bcol ^ ((row & 7) << 4)); }

// ================= fused user chain =================
// Z = relu(mean3@W3l^T + user_x@W3r^T + b3); out = Z@Wlin1^T + blin1
__global__ __launch_bounds__(256) void k_fused_u(
        const unsigned short* __restrict__ mean3, const unsigned short* __restrict__ user_x,
        const unsigned short* __restrict__ W3l, const unsigned short* __restrict__ W3r,
        const float* __restrict__ b3, const unsigned short* __restrict__ Wl1,
        const float* __restrict__ bl1, float* __restrict__ out, int M) {
    __shared__ unsigned short Z[128 * 128];
    const int lane = threadIdx.x & 63;
    const int wv = threadIdx.x >> 6;
    const int rbase = blockIdx.x * 128 + wv * 32;
    const int lr = lane & 15;
    const int kg = lane >> 4;

    short8 xa[2][4], xc[2][4];
#pragma unroll
    for (int t = 0; t < 2; ++t) {
        int row = min(rbase + t * 16 + lr, M - 1);
#pragma unroll
        for (int kt = 0; kt < 4; ++kt) {
            xa[t][kt] = *reinterpret_cast<const short8*>(
                mean3 + (size_t)row * HID + kt * 32 + kg * 8);
            xc[t][kt] = *reinterpret_cast<const short8*>(
                user_x + (size_t)row * HID + kt * 32 + kg * 8);
        }
    }

    f32x4 acc[2][8];
#pragma unroll
    for (int t = 0; t < 2; ++t)
#pragma unroll
        for (int c = 0; c < 8; ++c) acc[t][c] = (f32x4){0.f, 0.f, 0.f, 0.f};

#pragma unroll
    for (int cg = 0; cg < 8; ++cg) {
        short8 wl[4], wr[4];
#pragma unroll
        for (int kt = 0; kt < 4; ++kt) {
            wl[kt] = *reinterpret_cast<const short8*>(
                W3l + (size_t)(cg * 16 + lr) * HID + kt * 32 + kg * 8);
            wr[kt] = *reinterpret_cast<const short8*>(
                W3r + (size_t)(cg * 16 + lr) * HID + kt * 32 + kg * 8);
        }
#pragma unroll
        for (int kt = 0; kt < 4; ++kt)
#pragma unroll
            for (int t = 0; t < 2; ++t) {
                acc[t][cg] = __builtin_amdgcn_mfma_f32_16x16x32_bf16(
                    wl[kt], xa[t][kt], acc[t][cg], 0, 0, 0);
                acc[t][cg] = __builtin_amdgcn_mfma_f32_16x16x32_bf16(
                    wr[kt], xc[t][kt], acc[t][cg], 0, 0, 0);
            }
    }

    // epilogue 1: relu(acc + b3) -> swizzled LDS tile (bf16)
#pragma unroll
    for (int t = 0; t < 2; ++t) {
        const int ul = wv * 32 + t * 16 + lr;
#pragma unroll
        for (int cg = 0; cg < 8; ++cg) {
            const int h0 = cg * 16 + kg * 4;
            float4 vv = *reinterpret_cast<const float4*>(b3 + h0);
            float v0 = fmaxf(acc[t][cg][0] + vv.x, 0.f);
            float v1 = fmaxf(acc[t][cg][1] + vv.y, 0.f);
            float v2 = fmaxf(acc[t][cg][2] + vv.z, 0.f);
            float v3 = fmaxf(acc[t][cg][3] + vv.w, 0.f);
            uint2 pk = make_uint2(pk2(v0, v1), pk2(v2, v3));
            *reinterpret_cast<uint2*>((char*)Z + zswz(ul, h0 * 2)) = pk;
        }
    }
    __syncthreads();

    // GEMM2: out = Z @ Wlin1^T + blin1
    short8 zb[2][4];
#pragma unroll
    for (int t = 0; t < 2; ++t) {
        const int ul = wv * 32 + t * 16 + lr;
#pragma unroll
        for (int kt = 0; kt < 4; ++kt)
            zb[t][kt] = *reinterpret_cast<const short8*>(
                (char*)Z + zswz(ul, kt * 64 + kg * 16));
    }
    f32x4 a2[2][4];
#pragma unroll
    for (int t = 0; t < 2; ++t)
#pragma unroll
        for (int c = 0; c < 4; ++c) a2[t][c] = (f32x4){0.f, 0.f, 0.f, 0.f};
#pragma unroll
    for (int cg = 0; cg < 4; ++cg) {
        short8 wf[4];
#pragma unroll
        for (int kt = 0; kt < 4; ++kt)
            wf[kt] = *reinterpret_cast<const short8*>(
                Wl1 + (size_t)(cg * 16 + lr) * HID + kt * 32 + kg * 8);
#pragma unroll
        for (int kt = 0; kt < 4; ++kt)
#pragma unroll
            for (int t = 0; t < 2; ++t)
                a2[t][cg] = __builtin_amdgcn_mfma_f32_16x16x32_bf16(
                    wf[kt], zb[t][kt], a2[t][cg], 0, 0, 0);
    }
#pragma unroll
    for (int t = 0; t < 2; ++t) {
        const int u = rbase + t * 16 + lr;
        if (u >= M) continue;
#pragma unroll
        for (int cg = 0; cg < 4; ++cg) {
            const int o0 = cg * 16 + kg * 4;
            float4 bb = *reinterpret_cast<const float4*>(bl1 + o0);
            float4 o = make_float4(a2[t][cg][0] + bb.x, a2[t][cg][1] + bb.y,
                                   a2[t][cg][2] + bb.z, a2[t][cg][3] + bb.w);
            *reinterpret_cast<float4*>(out + (size_t)u * OUTD + o0) = o;
        }
    }
}

// ================= fused movie chain =================
// Z = relu(mean2@W2l^T + mxb@W2r^T + b2); movie_z = Z; out = Z@Wlin2^T + blin2
__global__ __launch_bounds__(256) void k_fused_m(
        const unsigned short* __restrict__ mean2, const unsigned short* __restrict__ mxb,
        const unsigned short* __restrict__ W2l, const unsigned short* __restrict__ W2r,
        const float* __restrict__ b2, unsigned short* __restrict__ movie_z,
        const unsigned short* __restrict__ Wl2, const float* __restrict__ bl2,
        float* __restrict__ out, int M) {
    __shared__ unsigned short Z[128 * 128];
    const int lane = threadIdx.x & 63;
    const int wv = threadIdx.x >> 6;
    const int rbase = blockIdx.x * 128 + wv * 32;
    const int lr = lane & 15;
    const int kg = lane >> 4;

    short8 xa[2][4], xc[2][2];
#pragma unroll
    for (int t = 0; t < 2; ++t) {
        int row = min(rbase + t * 16 + lr, M - 1);
#pragma unroll
        for (int kt = 0; kt < 4; ++kt)
            xa[t][kt] = *reinterpret_cast<const short8*>(
                mean2 + (size_t)row * HID + kt * 32 + kg * 8);
#pragma unroll
        for (int kt = 0; kt < 2; ++kt)
            xc[t][kt] = *reinterpret_cast<const short8*>(
                mxb + (size_t)row * FEAT + kt * 32 + kg * 8);
    }

    f32x4 acc[2][8];
#pragma unroll
    for (int t = 0; t < 2; ++t)
#pragma unroll
        for (int c = 0; c < 8; ++c) acc[t][c] = (f32x4){0.f, 0.f, 0.f, 0.f};

#pragma unroll
    for (int cg = 0; cg < 8; ++cg) {
        short8 wl[4], wr[2];
#pragma unroll
        for (int kt = 0; kt < 4; ++kt)
            wl[kt] = *reinterpret_cast<const short8*>(
                W2l + (size_t)(cg * 16 + lr) * HID + kt * 32 + kg * 8);
#pragma unroll
        for (int kt = 0; kt < 2; ++kt)
            wr[kt] = *reinterpret_cast<const short8*>(
                W2r + (size_t)(cg * 16 + lr) * FEAT + kt * 32 + kg * 8);
#pragma unroll
        for (int kt = 0; kt < 4; ++kt)
#pragma unroll
            for (int t = 0; t < 2; ++t)
                acc[t][cg] = __builtin_amdgcn_mfma_f32_16x16x32_bf16(
                    wl[kt], xa[t][kt], acc[t][cg], 0, 0, 0);
#pragma unroll
        for (int kt = 0; kt < 2; ++kt)
#pragma unroll
            for (int t = 0; t < 2; ++t)
                acc[t][cg] = __builtin_amdgcn_mfma_f32_16x16x32_bf16(
                    wr[kt], xc[t][kt], acc[t][cg], 0, 0, 0);
    }

    // epilogue 1: relu(acc + b2) -> LDS + global movie_z
#pragma unroll
    for (int t = 0; t < 2; ++t) {
        const int ul = wv * 32 + t * 16 + lr;
        const int u = rbase + t * 16 + lr;
#pragma unroll
        for (int cg = 0; cg < 8; ++cg) {
            const int h0 = cg * 16 + kg * 4;
            float4 vv = *reinterpret_cast<const float4*>(b2 + h0);
            float v0 = fmaxf(acc[t][cg][0] + vv.x, 0.f);
            float v1 = fmaxf(acc[t][cg][1] + vv.y, 0.f);
            float v2 = fmaxf(acc[t][cg][2] + vv.z, 0.f);
            float v3 = fmaxf(acc[t][cg][3] + vv.w, 0.f);
            uint2 pk = make_uint2(pk2(v0, v1), pk2(v2, v3));
            *reinterpret_cast<uint2*>((char*)Z + zswz(ul, h0 * 2)) = pk;
            if (u < M)
                *reinterpret_cast<uint2*>(movie_z + (size_t)u * HID + h0) = pk;
        }
    }
    __syncthreads();

    // GEMM2: out = Z @ Wlin2^T + blin2
    short8 zb[2][4];
#pragma unroll
    for (int t = 0; t < 2; ++t) {
        const int ul = wv * 32 + t * 16 + lr;
#pragma unroll
        for (int kt = 0; kt < 4; ++kt)
            zb[t][kt] = *reinterpret_cast<const short8*>(
                (char*)Z + zswz(ul, kt * 64 + kg * 16));
    }
    f32x4 a2[2][4];
#pragma unroll
    for (int t = 0; t < 2; ++t)
#pragma unroll
        for (int c = 0; c < 4; ++c) a2[t][c] = (f32x4){0.f, 0.f, 0.f, 0.f};
#pragma unroll
    for (int cg = 0; cg < 4; ++cg) {
        short8 wf[4];
#pragma unroll
        for (int kt = 0; kt < 4; ++kt)
            wf[kt] = *reinterpret_cast<const short8*>(
                Wl2 + (size_t)(cg * 16 + lr) * HID + kt * 32 + kg * 8);
#pragma unroll
        for (int kt = 0; kt < 4; ++kt)
#pragma unroll
            for (int t = 0; t < 2; ++t)
                a2[t][cg] = __builtin_amdgcn_mfma_f32_16x16x32_bf16(
                    wf[kt], zb[t][kt], a2[t][cg], 0, 0, 0);
    }
#pragma unroll
    for (int t = 0; t < 2; ++t) {
        const int u = rbase + t * 16 + lr;
        if (u >= M) continue;
#pragma unroll
        for (int cg = 0; cg < 4; ++cg) {
            const int o0 = cg * 16 + kg * 4;
            float4 bb = *reinterpret_cast<const float4*>(bl2 + o0);
            float4 o = make_float4(a2[t][cg][0] + bb.x, a2[t][cg][1] + bb.y,
                                   a2[t][cg][2] + bb.z, a2[t][cg][3] + bb.w);
            *reinterpret_cast<float4*>(out + (size_t)u * OUTD + o0) = o;
        }
    }
}

// ---------------- new_index output ----------------
__global__ void k_index(const int* __restrict__ t, float* __restrict__ o, int n, int nu) {
    int i = blockIdx.x * blockDim.x + threadIdx.x;
    if (i < n) {
        o[i] = (float)t[i];
        o[n + i] = (float)(t[n + i] + nu);
    }
}

extern "C" void kernel_launch(void* const* d_in, const int* in_sizes, int n_in,
                              void* d_out, int out_size, void* d_ws, size_t ws_size,
                              hipStream_t stream) {
    const float* movie_x  = (const float*)d_in[0];
    const int*   user_idx = (const int*)d_in[1];
    const int*   movie_idx= (const int*)d_in[2];
    const int*   tuples   = (const int*)d_in[3];
    const float* user_emb = (const float*)d_in[4];
    const float* W1l = (const float*)d_in[5];
    const float* b1  = (const float*)d_in[6];
    const float* W1r = (const float*)d_in[7];
    const float* W2l = (const float*)d_in[8];
    const float* b2  = (const float*)d_in[9];
    const float* W2r = (const float*)d_in[10];
    const float* W3l = (const float*)d_in[11];
    const float* b3  = (const float*)d_in[12];
    const float* W3r = (const float*)d_in[13];
    const float* Wlin1 = (const float*)d_in[14];
    const float* blin1 = (const float*)d_in[15];
    const float* Wlin2 = (const float*)d_in[16];
    const float* blin2 = (const float*)d_in[17];

    float* out = (float*)d_out;

    // ---- workspace layout ----
    char* p = (char*)d_ws;
    int* ghist = (int*)p;  p += 360 * 4;
    int* bb    = (int*)p;  p += 360 * 4;
    int* gcur  = (int*)p;  p += 360 * 4;
    int* entries = (int*)p; p += (size_t)NLIST * 4;
    int* rp    = (int*)p;  p += (size_t)(NTOT + 8) * 4;
    int* list  = (int*)p;  p += (size_t)NLIST * 4;
    float* c1  = (float*)p; p += 128 * 4;
    unsigned short* wb = (unsigned short*)p; p += (size_t)CVT_TOT * 2;
    unsigned short* W1l_b  = wb;
    unsigned short* W2l_b  = wb + 8192;
    unsigned short* W2r_b  = wb + 24576;
    unsigned short* W3l_b  = wb + 32768;
    unsigned short* W3r_b  = wb + 49152;
    unsigned short* Wlin1_b= wb + 65536;
    unsigned short* Wlin2_b= wb + 73728;
    unsigned short* mxb    = wb + 81920;                              // [NM][64]
    unsigned short* mean1  = (unsigned short*)p; p += (size_t)NU * FEAT * 2;
    unsigned short* user_x = (unsigned short*)p; p += (size_t)NU * HID * 2;
    unsigned short* mean2  = (unsigned short*)p; p += (size_t)NM * HID * 2;
    unsigned short* movie_z= (unsigned short*)p; p += (size_t)NM * HID * 2;
    unsigned short* mean3  = (unsigned short*)p; p += (size_t)NU * HID * 2;

    // ---- CSR build ----
    hipMemsetAsync(ghist, 0, NBUCK * sizeof(int), stream);
    k_hist<<<NPBLK, 256, 0, stream>>>(user_idx, movie_idx, ghist);
    k_bscan<<<1, 512, 0, stream>>>(ghist, bb, gcur);
    k_part<<<NPBLK, 256, 0, stream>>>(user_idx, movie_idx, gcur, entries);
    k_csr<<<NBUCK, 256, 0, stream>>>(bb, entries, rp, list);

    // ---- conversions + c1 ----
    k_cvt<<<(CVT_TOT + 255) / 256, 256, 0, stream>>>(W1l, W2l, W2r, W3l, W3r,
                                                     Wlin1, Wlin2, movie_x, wb);
    k_c1<<<1, 128, 0, stream>>>(user_emb, W1r, b1, c1);

    // ---- conv1: gather + GEMM -> user_x ----
    k_gather_b<FEAT><<<(NU + 31) / 32, 256, 0, stream>>>(mxb, rp, list, mean1, 0, NU);
    k_mf2<FEAT, HID, true, true, false><<<(NU + 127) / 128, 256, 0, stream>>>(
        mean1, W1l_b, c1, user_x, NU);

    // ---- conv2 + lin2 (fused movie chain) ----
    k_gather_b<HID><<<(NM + 15) / 16, 256, 0, stream>>>(user_x, rp, list, mean2, NU, NM);
    k_fused_m<<<(NM + 127) / 128, 256, 0, stream>>>(
        mean2, mxb, W2l_b, W2r_b, b2, movie_z, Wlin2_b, blin2,
        out + (size_t)NU * OUTD, NM);

    // ---- conv3 + lin1 (fused user chain; t3 computed inline from user_x) ----
    k_gather_b<HID><<<(NU + 15) / 16, 256, 0, stream>>>(movie_z, rp, list, mean3, 0, NU);
    k_fused_u<<<(NU + 127) / 128, 256, 0, stream>>>(
        mean3, user_x, W3l_b, W3r_b, b3, Wlin1_b, blin1, out, NU);

    // ---- new_index ----
    k_index<<<(100000 + 255) / 256, 256, 0, stream>>>(
        tuples, out + (size_t)(NU + NM) * OUTD, 100000, NU);
}

// Round 7
// 186.628 us; speedup vs baseline: 29.8818x; 1.1476x over previous
//
#include <hip/hip_runtime.h>

typedef __attribute__((ext_vector_type(8))) short short8;   // 8 bf16 (4 VGPR)
typedef __attribute__((ext_vector_type(4))) float f32x4;    // MFMA acc

static const int NU = 100000;
static const int NM = 20000;
static const int NE = 600000;
static const int FEAT = 64;
static const int HID = 128;
static const int OUTD = 64;
static const int NTOT = NU + NM;
static const int NLIST = 2 * NE;
static const int CVT_TOT = 81920 + NM * FEAT;   // weights + movie_x

// bucket geometry: users 512 nodes/bucket, movies 128 nodes/bucket
static const int UB_SHIFT = 9;
static const int MB_SHIFT = 7;
static const int NBU = (NU + 511) >> 9;           // 196
static const int NBM = (NM + 127) >> 7;           // 157
static const int NBUCK = NBU + NBM;               // 353
static const int EPB = 4096;
static const int NPBLK = (NE + EPB - 1) / EPB;    // 147

__device__ inline float b2f(unsigned short h) {
    unsigned int u = ((unsigned int)h) << 16;
    float f; __builtin_memcpy(&f, &u, 4); return f;
}
__device__ inline unsigned short f2b(float f) {
    unsigned int u; __builtin_memcpy(&u, &f, 4);
    u += 0x7FFFu + ((u >> 16) & 1u);            // RNE
    return (unsigned short)(u >> 16);
}
__device__ inline unsigned int pk2(float a, float b) {
    return (unsigned int)f2b(a) | ((unsigned int)f2b(b) << 16);
}
// XOR swizzle within a row: spreads the 16B frag slots across banks (G4)
__device__ inline int wswz(int row, int bc, int rowbytes) {
    return row * rowbytes + (bc ^ ((row & 7) << 4));
}

// ---------------- CSR build (hist -> scan -> partition -> per-bucket CSR) ----------------
__global__ __launch_bounds__(256) void k_hist(const int* __restrict__ ui,
                                              const int* __restrict__ mi,
                                              int* __restrict__ ghist) {
    __shared__ int h[NBUCK];
    const int tid = threadIdx.x;
    for (int i = tid; i < NBUCK; i += 256) h[i] = 0;
    __syncthreads();
#pragma unroll
    for (int it = 0; it < EPB / 256; ++it) {
        int e = blockIdx.x * EPB + it * 256 + tid;
        if (e < NE) {
            atomicAdd(&h[ui[e] >> UB_SHIFT], 1);
            atomicAdd(&h[NBU + (mi[e] >> MB_SHIFT)], 1);
        }
    }
    __syncthreads();
    for (int i = tid; i < NBUCK; i += 256)
        if (h[i]) atomicAdd(&ghist[i], h[i]);
}

__global__ __launch_bounds__(512) void k_bscan(const int* __restrict__ ghist,
                                               int* __restrict__ bb,
                                               int* __restrict__ gcur) {
    __shared__ int s[512];
    const int tid = threadIdx.x;
    int v = (tid < NBUCK) ? ghist[tid] : 0;
    s[tid] = v;
    __syncthreads();
#pragma unroll
    for (int off = 1; off < 512; off <<= 1) {
        int x = (tid >= off) ? s[tid - off] : 0;
        __syncthreads();
        s[tid] += x;
        __syncthreads();
    }
    int excl = s[tid] - v;
    if (tid < NBUCK) { bb[tid] = excl; gcur[tid] = excl; }
    if (tid == 511) bb[NBUCK] = s[511];
}

__global__ __launch_bounds__(256) void k_part(const int* __restrict__ ui,
                                              const int* __restrict__ mi,
                                              int* __restrict__ gcur,
                                              int* __restrict__ entries) {
    __shared__ int h[NBUCK], base[NBUCK], cur[NBUCK];
    const int tid = threadIdx.x;
    for (int i = tid; i < NBUCK; i += 256) h[i] = 0;
    __syncthreads();

    int eu[EPB / 256], em[EPB / 256];
#pragma unroll
    for (int it = 0; it < EPB / 256; ++it) {
        int e = blockIdx.x * EPB + it * 256 + tid;
        if (e < NE) {
            eu[it] = ui[e]; em[it] = mi[e];
            atomicAdd(&h[eu[it] >> UB_SHIFT], 1);
            atomicAdd(&h[NBU + (em[it] >> MB_SHIFT)], 1);
        } else eu[it] = -1;
    }
    __syncthreads();
    for (int i = tid; i < NBUCK; i += 256) {
        int c = h[i];
        base[i] = c ? atomicAdd(&gcur[i], c) : 0;
        cur[i] = 0;
    }
    __syncthreads();
#pragma unroll
    for (int it = 0; it < EPB / 256; ++it) {
        if (eu[it] < 0) continue;
        int u = eu[it], m = em[it];
        int bu = u >> UB_SHIFT;
        int o1 = base[bu] + atomicAdd(&cur[bu], 1);
        entries[o1] = (m << UB_SHIFT) | (u & 511);
        int bm = NBU + (m >> MB_SHIFT);
        int o2 = base[bm] + atomicAdd(&cur[bm], 1);
        entries[o2] = (u << MB_SHIFT) | (m & 127);
    }
}

__global__ __launch_bounds__(256) void k_csr(const int* __restrict__ bb,
                                             const int* __restrict__ entries,
                                             int* __restrict__ rp,
                                             int* __restrict__ list) {
    __shared__ int lcnt[512], lrp[512], lcur[512], ps[256];
    const int b = blockIdx.x;
    const int tid = threadIdx.x;
    const int s = bb[b], e = bb[b + 1];
    const bool isU = b < NBU;
    const int shift = isU ? UB_SHIFT : MB_SHIFT;
    const int mask = isU ? 511 : 127;
    const int n0 = isU ? (b << UB_SHIFT) : ((b - NBU) << MB_SHIFT);
    const int nNodes = isU ? min(512, NU - n0) : min(128, NM - n0);
    const int g0 = isU ? n0 : NU + n0;

    for (int i = tid; i < 512; i += 256) { lcnt[i] = 0; lcur[i] = 0; }
    __syncthreads();
    for (int i = s + tid; i < e; i += 256)
        atomicAdd(&lcnt[entries[i] & mask], 1);
    __syncthreads();
    int a0 = lcnt[2 * tid], a1 = lcnt[2 * tid + 1];
    int pr = a0 + a1;
    ps[tid] = pr;
    __syncthreads();
#pragma unroll
    for (int off = 1; off < 256; off <<= 1) {
        int x = (tid >= off) ? ps[tid - off] : 0;
        __syncthreads();
        ps[tid] += x;
        __syncthreads();
    }
    int excl = ps[tid] - pr;
    lrp[2 * tid] = excl;
    lrp[2 * tid + 1] = excl + a0;
    __syncthreads();
    for (int i = tid; i < nNodes; i += 256) rp[g0 + i] = s + lrp[i];
    if (b == NBUCK - 1 && tid == 0) rp[NTOT] = e;
    for (int i = s + tid; i < e; i += 256) {
        int p = entries[i];
        int dl = p & mask;
        int off = s + lrp[dl] + atomicAdd(&lcur[dl], 1);
        list[off] = p >> shift;
    }
}

// ---------------- fp32 -> bf16 conversion (weights + movie_x) ----------------
__global__ void k_cvt(const float* __restrict__ w1l, const float* __restrict__ w2l,
                      const float* __restrict__ w2r, const float* __restrict__ w3l,
                      const float* __restrict__ w3r, const float* __restrict__ wl1,
                      const float* __restrict__ wl2, const float* __restrict__ mx,
                      unsigned short* __restrict__ dst) {
    int g = blockIdx.x * blockDim.x + threadIdx.x;
    if (g >= CVT_TOT) return;
    const float* s; int o;
    if      (g < 8192)   { s = w1l; o = g; }
    else if (g < 24576)  { s = w2l; o = g - 8192; }
    else if (g < 32768)  { s = w2r; o = g - 24576; }
    else if (g < 49152)  { s = w3l; o = g - 32768; }
    else if (g < 65536)  { s = w3r; o = g - 49152; }
    else if (g < 73728)  { s = wl1; o = g - 65536; }
    else if (g < 81920)  { s = wl2; o = g - 73728; }
    else                 { s = mx;  o = g - 81920; }
    dst[g] = f2b(s[o]);
}

// ---------------- c1 = b1 + user_emb @ W1r^T ----------------
__global__ void k_c1(const float* __restrict__ ue, const float* __restrict__ w1r,
                     const float* __restrict__ b1, float* __restrict__ c1) {
    int h = threadIdx.x;
    float a = 0.f;
#pragma unroll 16
    for (int k = 0; k < HID; ++k) a += ue[k] * w1r[h * HID + k];
    c1[h] = a + b1[h];
}

// ---------------- bf16 gather-based segment mean ----------------
template<int C>
__global__ __launch_bounds__(256) void k_gather_b(const unsigned short* __restrict__ src,
                                                  const int* __restrict__ rp,
                                                  const int* __restrict__ list,
                                                  unsigned short* __restrict__ dst,
                                                  int base, int n) {
    constexpr int TPN = C / 8;
    constexpr int NPB = 256 / TPN;
    const int node = blockIdx.x * NPB + threadIdx.x / TPN;
    if (node >= n) return;
    const int c8 = (threadIdx.x % TPN) * 8;
    const int g = base + node;
    const int s = rp[g], e = rp[g + 1];

    float a[8];
#pragma unroll
    for (int j = 0; j < 8; ++j) a[j] = 0.f;

    int i = s;
    for (; i + 1 < e; i += 2) {
        int r0 = list[i], r1 = list[i + 1];
        short8 v0 = *reinterpret_cast<const short8*>(src + (size_t)r0 * C + c8);
        short8 v1 = *reinterpret_cast<const short8*>(src + (size_t)r1 * C + c8);
#pragma unroll
        for (int j = 0; j < 8; ++j)
            a[j] += b2f((unsigned short)v0[j]) + b2f((unsigned short)v1[j]);
    }
    if (i < e) {
        int r0 = list[i];
        short8 v0 = *reinterpret_cast<const short8*>(src + (size_t)r0 * C + c8);
#pragma unroll
        for (int j = 0; j < 8; ++j) a[j] += b2f((unsigned short)v0[j]);
    }
    const float sc = 1.0f / (float)max(e - s, 1);
    short8 o;
#pragma unroll
    for (int j = 0; j < 8; ++j) o[j] = (short)f2b(a[j] * sc);
    *reinterpret_cast<short8*>(dst + (size_t)node * C + c8) = o;
}

// ================= swapped-operand MFMA GEMM, W staged in LDS =================
// Y[u][h] = [relu]( X[u][:] @ W[h][:]^T + vec[h] )
template<int K, int NO, bool AVEC, bool RELU, bool F32OUT>
__global__ __launch_bounds__(256) void k_mf2(const unsigned short* __restrict__ X,
                                             const unsigned short* __restrict__ W,
                                             const float* __restrict__ vec,
                                             void* __restrict__ Yv, int M) {
    constexpr int KT = K / 32;
    constexpr int CG = NO / 16;
    constexpr int WB = NO * K * 2;         // weight bytes
    constexpr int RB = K * 2;              // row bytes
    __shared__ __align__(16) char lds[WB];
    const int tid = threadIdx.x;
    const int lane = tid & 63;
    const int wv = tid >> 6;
    const int rbase = blockIdx.x * 128 + wv * 32;
    const int lr = lane & 15;
    const int kg = lane >> 4;

    // stage W (coalesced, swizzled)
#pragma unroll
    for (int i = 0; i < WB / 16 / 256; ++i) {
        int idx = tid + i * 256;
        int row = idx / (RB / 16);
        int bc = (idx % (RB / 16)) * 16;
        *reinterpret_cast<uint4*>(lds + wswz(row, bc, RB)) =
            *reinterpret_cast<const uint4*>((const char*)W + idx * 16);
    }

    short8 xb[2][KT];
#pragma unroll
    for (int t = 0; t < 2; ++t) {
        int row = min(rbase + t * 16 + lr, M - 1);
#pragma unroll
        for (int kt = 0; kt < KT; ++kt)
            xb[t][kt] = *reinterpret_cast<const short8*>(
                X + (size_t)row * K + kt * 32 + kg * 8);
    }
    __syncthreads();

    f32x4 acc[2][CG];
#pragma unroll
    for (int t = 0; t < 2; ++t)
#pragma unroll
        for (int c = 0; c < CG; ++c) acc[t][c] = (f32x4){0.f, 0.f, 0.f, 0.f};

#pragma unroll
    for (int cg = 0; cg < CG; ++cg) {
        short8 wf[KT];
#pragma unroll
        for (int kt = 0; kt < KT; ++kt)
            wf[kt] = *reinterpret_cast<const short8*>(
                lds + wswz(cg * 16 + lr, kt * 64 + kg * 16, RB));
#pragma unroll
        for (int kt = 0; kt < KT; ++kt)
#pragma unroll
            for (int t = 0; t < 2; ++t)
                acc[t][cg] = __builtin_amdgcn_mfma_f32_16x16x32_bf16(
                    wf[kt], xb[t][kt], acc[t][cg], 0, 0, 0);
    }

#pragma unroll
    for (int t = 0; t < 2; ++t) {
        const int u = rbase + t * 16 + lr;
        if (u >= M) continue;
#pragma unroll
        for (int cg = 0; cg < CG; ++cg) {
            const int h0 = cg * 16 + kg * 4;
            float v[4];
#pragma unroll
            for (int r = 0; r < 4; ++r) v[r] = acc[t][cg][r];
            if (AVEC) {
                float4 vv = *reinterpret_cast<const float4*>(vec + h0);
                v[0] += vv.x; v[1] += vv.y; v[2] += vv.z; v[3] += vv.w;
            }
            if (RELU)
#pragma unroll
                for (int r = 0; r < 4; ++r) v[r] = fmaxf(v[r], 0.f);
            if (F32OUT) {
                float4 o = make_float4(v[0], v[1], v[2], v[3]);
                *reinterpret_cast<float4*>((float*)Yv + (size_t)u * NO + h0) = o;
            } else {
                uint2 o = make_uint2(pk2(v[0], v[1]), pk2(v[2], v[3]));
                *reinterpret_cast<uint2*>((unsigned short*)Yv + (size_t)u * NO + h0) = o;
            }
        }
    }
}

// ================= fused user chain (weights in LDS, Z aliases W3l) =================
// Z = relu(mean3@W3l^T + user_x@W3r^T + b3); out = Z@Wlin1^T + blin1
__global__ __launch_bounds__(256) void k_fused_u(
        const unsigned short* __restrict__ mean3, const unsigned short* __restrict__ user_x,
        const unsigned short* __restrict__ W3l, const unsigned short* __restrict__ W3r,
        const float* __restrict__ b3, const unsigned short* __restrict__ Wl1,
        const float* __restrict__ bl1, float* __restrict__ out, int M) {
    __shared__ __align__(16) char lds[65536];   // [0,32K) W3l -> Z; [32K,64K) W3r -> Wl1
    const int tid = threadIdx.x;
    const int lane = tid & 63;
    const int wv = tid >> 6;
    const int rbase = blockIdx.x * 128 + wv * 32;
    const int lr = lane & 15;
    const int kg = lane >> 4;

    // stage W3l + W3r (32KB each; 2048 16B-chunks; 16 chunks/row)
#pragma unroll
    for (int i = 0; i < 8; ++i) {
        int idx = tid + i * 256;
        int row = idx >> 4, bc = (idx & 15) << 4;
        int sw = wswz(row, bc, 256);
        *reinterpret_cast<uint4*>(lds + sw) =
            *reinterpret_cast<const uint4*>((const char*)W3l + idx * 16);
        *reinterpret_cast<uint4*>(lds + 32768 + sw) =
            *reinterpret_cast<const uint4*>((const char*)W3r + idx * 16);
    }

    short8 xa[2][4], xc[2][4];
#pragma unroll
    for (int t = 0; t < 2; ++t) {
        int row = min(rbase + t * 16 + lr, M - 1);
#pragma unroll
        for (int kt = 0; kt < 4; ++kt) {
            xa[t][kt] = *reinterpret_cast<const short8*>(
                mean3 + (size_t)row * HID + kt * 32 + kg * 8);
            xc[t][kt] = *reinterpret_cast<const short8*>(
                user_x + (size_t)row * HID + kt * 32 + kg * 8);
        }
    }
    __syncthreads();

    f32x4 acc[2][8];
#pragma unroll
    for (int t = 0; t < 2; ++t)
#pragma unroll
        for (int c = 0; c < 8; ++c) acc[t][c] = (f32x4){0.f, 0.f, 0.f, 0.f};

#pragma unroll
    for (int cg = 0; cg < 8; ++cg) {
        short8 wl[4], wr[4];
#pragma unroll
        for (int kt = 0; kt < 4; ++kt) {
            int sw = wswz(cg * 16 + lr, kt * 64 + kg * 16, 256);
            wl[kt] = *reinterpret_cast<const short8*>(lds + sw);
            wr[kt] = *reinterpret_cast<const short8*>(lds + 32768 + sw);
        }
#pragma unroll
        for (int kt = 0; kt < 4; ++kt)
#pragma unroll
            for (int t = 0; t < 2; ++t) {
                acc[t][cg] = __builtin_amdgcn_mfma_f32_16x16x32_bf16(
                    wl[kt], xa[t][kt], acc[t][cg], 0, 0, 0);
                acc[t][cg] = __builtin_amdgcn_mfma_f32_16x16x32_bf16(
                    wr[kt], xc[t][kt], acc[t][cg], 0, 0, 0);
            }
    }
    __syncthreads();   // all W3l/W3r reads done -> safe to overwrite

    // stage Wlin1 (16KB: [64][128] bf16, 256B rows) into upper half
#pragma unroll
    for (int i = 0; i < 4; ++i) {
        int idx = tid + i * 256;
        int row = idx >> 4, bc = (idx & 15) << 4;
        *reinterpret_cast<uint4*>(lds + 32768 + wswz(row, bc, 256)) =
            *reinterpret_cast<const uint4*>((const char*)Wl1 + idx * 16);
    }
    // epilogue 1: relu(acc + b3) -> swizzled Z tile over [0,32K)
#pragma unroll
    for (int t = 0; t < 2; ++t) {
        const int ul = wv * 32 + t * 16 + lr;
#pragma unroll
        for (int cg = 0; cg < 8; ++cg) {
            const int h0 = cg * 16 + kg * 4;
            float4 vv = *reinterpret_cast<const float4*>(b3 + h0);
            float v0 = fmaxf(acc[t][cg][0] + vv.x, 0.f);
            float v1 = fmaxf(acc[t][cg][1] + vv.y, 0.f);
            float v2 = fmaxf(acc[t][cg][2] + vv.z, 0.f);
            float v3 = fmaxf(acc[t][cg][3] + vv.w, 0.f);
            uint2 pk = make_uint2(pk2(v0, v1), pk2(v2, v3));
            *reinterpret_cast<uint2*>(lds + wswz(ul, h0 * 2, 256)) = pk;
        }
    }
    __syncthreads();

    // GEMM2: out = Z @ Wlin1^T + blin1 (all LDS-fed)
    short8 zb[2][4];
#pragma unroll
    for (int t = 0; t < 2; ++t) {
        const int ul = wv * 32 + t * 16 + lr;
#pragma unroll
        for (int kt = 0; kt < 4; ++kt)
            zb[t][kt] = *reinterpret_cast<const short8*>(
                lds + wswz(ul, kt * 64 + kg * 16, 256));
    }
    f32x4 a2[2][4];
#pragma unroll
    for (int t = 0; t < 2; ++t)
#pragma unroll
        for (int c = 0; c < 4; ++c) a2[t][c] = (f32x4){0.f, 0.f, 0.f, 0.f};
#pragma unroll
    for (int cg = 0; cg < 4; ++cg) {
        short8 wf[4];
#pragma unroll
        for (int kt = 0; kt < 4; ++kt)
            wf[kt] = *reinterpret_cast<const short8*>(
                lds + 32768 + wswz(cg * 16 + lr, kt * 64 + kg * 16, 256));
#pragma unroll
        for (int kt = 0; kt < 4; ++kt)
#pragma unroll
            for (int t = 0; t < 2; ++t)
                a2[t][cg] = __builtin_amdgcn_mfma_f32_16x16x32_bf16(
                    wf[kt], zb[t][kt], a2[t][cg], 0, 0, 0);
    }
#pragma unroll
    for (int t = 0; t < 2; ++t) {
        const int u = rbase + t * 16 + lr;
        if (u >= M) continue;
#pragma unroll
        for (int cg = 0; cg < 4; ++cg) {
            const int o0 = cg * 16 + kg * 4;
            float4 bb = *reinterpret_cast<const float4*>(bl1 + o0);
            float4 o = make_float4(a2[t][cg][0] + bb.x, a2[t][cg][1] + bb.y,
                                   a2[t][cg][2] + bb.z, a2[t][cg][3] + bb.w);
            *reinterpret_cast<float4*>(out + (size_t)u * OUTD + o0) = o;
        }
    }
}

// ================= fused movie chain (weights in LDS, Z aliases W2l) =================
// Z = relu(mean2@W2l^T + mxb@W2r^T + b2); movie_z = Z; out = Z@Wlin2^T + blin2
__global__ __launch_bounds__(256) void k_fused_m(
        const unsigned short* __restrict__ mean2, const unsigned short* __restrict__ mxb,
        const unsigned short* __restrict__ W2l, const unsigned short* __restrict__ W2r,
        const float* __restrict__ b2, unsigned short* __restrict__ movie_z,
        const unsigned short* __restrict__ Wl2, const float* __restrict__ bl2,
        float* __restrict__ out, int M) {
    __shared__ __align__(16) char lds[49152];   // [0,32K) W2l -> Z; [32K,48K) W2r -> Wl2
    const int tid = threadIdx.x;
    const int lane = tid & 63;
    const int wv = tid >> 6;
    const int rbase = blockIdx.x * 128 + wv * 32;
    const int lr = lane & 15;
    const int kg = lane >> 4;

    // stage W2l (32KB, 256B rows) and W2r (16KB, 128B rows)
#pragma unroll
    for (int i = 0; i < 8; ++i) {
        int idx = tid + i * 256;
        int row = idx >> 4, bc = (idx & 15) << 4;
        *reinterpret_cast<uint4*>(lds + wswz(row, bc, 256)) =
            *reinterpret_cast<const uint4*>((const char*)W2l + idx * 16);
    }
#pragma unroll
    for (int i = 0; i < 4; ++i) {
        int idx = tid + i * 256;
        int row = idx >> 3, bc = (idx & 7) << 4;
        *reinterpret_cast<uint4*>(lds + 32768 + wswz(row, bc, 128)) =
            *reinterpret_cast<const uint4*>((const char*)W2r + idx * 16);
    }

    short8 xa[2][4], xc[2][2];
#pragma unroll
    for (int t = 0; t < 2; ++t) {
        int row = min(rbase + t * 16 + lr, M - 1);
#pragma unroll
        for (int kt = 0; kt < 4; ++kt)
            xa[t][kt] = *reinterpret_cast<const short8*>(
                mean2 + (size_t)row * HID + kt * 32 + kg * 8);
#pragma unroll
        for (int kt = 0; kt < 2; ++kt)
            xc[t][kt] = *reinterpret_cast<const short8*>(
                mxb + (size_t)row * FEAT + kt * 32 + kg * 8);
    }
    __syncthreads();

    f32x4 acc[2][8];
#pragma unroll
    for (int t = 0; t < 2; ++t)
#pragma unroll
        for (int c = 0; c < 8; ++c) acc[t][c] = (f32x4){0.f, 0.f, 0.f, 0.f};

#pragma unroll
    for (int cg = 0; cg < 8; ++cg) {
        short8 wl[4], wr[2];
#pragma unroll
        for (int kt = 0; kt < 4; ++kt)
            wl[kt] = *reinterpret_cast<const short8*>(
                lds + wswz(cg * 16 + lr, kt * 64 + kg * 16, 256));
#pragma unroll
        for (int kt = 0; kt < 2; ++kt)
            wr[kt] = *reinterpret_cast<const short8*>(
                lds + 32768 + wswz(cg * 16 + lr, kt * 64 + kg * 16, 128));
#pragma unroll
        for (int kt = 0; kt < 4; ++kt)
#pragma unroll
            for (int t = 0; t < 2; ++t)
                acc[t][cg] = __builtin_amdgcn_mfma_f32_16x16x32_bf16(
                    wl[kt], xa[t][kt], acc[t][cg], 0, 0, 0);
#pragma unroll
        for (int kt = 0; kt < 2; ++kt)
#pragma unroll
            for (int t = 0; t < 2; ++t)
                acc[t][cg] = __builtin_amdgcn_mfma_f32_16x16x32_bf16(
                    wr[kt], xc[t][kt], acc[t][cg], 0, 0, 0);
    }
    __syncthreads();   // weight reads done -> safe to overwrite

    // stage Wlin2 (16KB, 256B rows) over W2r
#pragma unroll
    for (int i = 0; i < 4; ++i) {
        int idx = tid + i * 256;
        int row = idx >> 4, bc = (idx & 15) << 4;
        *reinterpret_cast<uint4*>(lds + 32768 + wswz(row, bc, 256)) =
            *reinterpret_cast<const uint4*>((const char*)Wl2 + idx * 16);
    }
    // epilogue 1: relu(acc + b2) -> Z (LDS) + global movie_z
#pragma unroll
    for (int t = 0; t < 2; ++t) {
        const int ul = wv * 32 + t * 16 + lr;
        const int u = rbase + t * 16 + lr;
#pragma unroll
        for (int cg = 0; cg < 8; ++cg) {
            const int h0 = cg * 16 + kg * 4;
            float4 vv = *reinterpret_cast<const float4*>(b2 + h0);
            float v0 = fmaxf(acc[t][cg][0] + vv.x, 0.f);
            float v1 = fmaxf(acc[t][cg][1] + vv.y, 0.f);
            float v2 = fmaxf(acc[t][cg][2] + vv.z, 0.f);
            float v3 = fmaxf(acc[t][cg][3] + vv.w, 0.f);
            uint2 pk = make_uint2(pk2(v0, v1), pk2(v2, v3));
            *reinterpret_cast<uint2*>(lds + wswz(ul, h0 * 2, 256)) = pk;
            if (u < M)
                *reinterpret_cast<uint2*>(movie_z + (size_t)u * HID + h0) = pk;
        }
    }
    __syncthreads();

    // GEMM2: out = Z @ Wlin2^T + blin2 (all LDS-fed)
    short8 zb[2][4];
#pragma unroll
    for (int t = 0; t < 2; ++t) {
        const int ul = wv * 32 + t * 16 + lr;
#pragma unroll
        for (int kt = 0; kt < 4; ++kt)
            zb[t][kt] = *reinterpret_cast<const short8*>(
                lds + wswz(ul, kt * 64 + kg * 16, 256));
    }
    f32x4 a2[2][4];
#pragma unroll
    for (int t = 0; t < 2; ++t)
#pragma unroll
        for (int c = 0; c < 4; ++c) a2[t][c] = (f32x4){0.f, 0.f, 0.f, 0.f};
#pragma unroll
    for (int cg = 0; cg < 4; ++cg) {
        short8 wf[4];
#pragma unroll
        for (int kt = 0; kt < 4; ++kt)
            wf[kt] = *reinterpret_cast<const short8*>(
                lds + 32768 + wswz(cg * 16 + lr, kt * 64 + kg * 16, 256));
#pragma unroll
        for (int kt = 0; kt < 4; ++kt)
#pragma unroll
            for (int t = 0; t < 2; ++t)
                a2[t][cg] = __builtin_amdgcn_mfma_f32_16x16x32_bf16(
                    wf[kt], zb[t][kt], a2[t][cg], 0, 0, 0);
    }
#pragma unroll
    for (int t = 0; t < 2; ++t) {
        const int u = rbase + t * 16 + lr;
        if (u >= M) continue;
#pragma unroll
        for (int cg = 0; cg < 4; ++cg) {
            const int o0 = cg * 16 + kg * 4;
            float4 bb = *reinterpret_cast<const float4*>(bl2 + o0);
            float4 o = make_float4(a2[t][cg][0] + bb.x, a2[t][cg][1] + bb.y,
                                   a2[t][cg][2] + bb.z, a2[t][cg][3] + bb.w);
            *reinterpret_cast<float4*>(out + (size_t)u * OUTD + o0) = o;
        }
    }
}

// ---------------- new_index output ----------------
__global__ void k_index(const int* __restrict__ t, float* __restrict__ o, int n, int nu) {
    int i = blockIdx.x * blockDim.x + threadIdx.x;
    if (i < n) {
        o[i] = (float)t[i];
        o[n + i] = (float)(t[n + i] + nu);
    }
}

extern "C" void kernel_launch(void* const* d_in, const int* in_sizes, int n_in,
                              void* d_out, int out_size, void* d_ws, size_t ws_size,
                              hipStream_t stream) {
    const float* movie_x  = (const float*)d_in[0];
    const int*   user_idx = (const int*)d_in[1];
    const int*   movie_idx= (const int*)d_in[2];
    const int*   tuples   = (const int*)d_in[3];
    const float* user_emb = (const float*)d_in[4];
    const float* W1l = (const float*)d_in[5];
    const float* b1  = (const float*)d_in[6];
    const float* W1r = (const float*)d_in[7];
    const float* W2l = (const float*)d_in[8];
    const float* b2  = (const float*)d_in[9];
    const float* W2r = (const float*)d_in[10];
    const float* W3l = (const float*)d_in[11];
    const float* b3  = (const float*)d_in[12];
    const float* W3r = (const float*)d_in[13];
    const float* Wlin1 = (const float*)d_in[14];
    const float* blin1 = (const float*)d_in[15];
    const float* Wlin2 = (const float*)d_in[16];
    const float* blin2 = (const float*)d_in[17];

    float* out = (float*)d_out;

    // ---- workspace layout ----
    char* p = (char*)d_ws;
    int* ghist = (int*)p;  p += 360 * 4;
    int* bb    = (int*)p;  p += 360 * 4;
    int* gcur  = (int*)p;  p += 360 * 4;
    int* entries = (int*)p; p += (size_t)NLIST * 4;
    int* rp    = (int*)p;  p += (size_t)(NTOT + 8) * 4;
    int* list  = (int*)p;  p += (size_t)NLIST * 4;
    float* c1  = (float*)p; p += 128 * 4;
    unsigned short* wb = (unsigned short*)p; p += (size_t)CVT_TOT * 2;
    unsigned short* W1l_b  = wb;
    unsigned short* W2l_b  = wb + 8192;
    unsigned short* W2r_b  = wb + 24576;
    unsigned short* W3l_b  = wb + 32768;
    unsigned short* W3r_b  = wb + 49152;
    unsigned short* Wlin1_b= wb + 65536;
    unsigned short* Wlin2_b= wb + 73728;
    unsigned short* mxb    = wb + 81920;                              // [NM][64]
    unsigned short* mean1  = (unsigned short*)p; p += (size_t)NU * FEAT * 2;
    unsigned short* user_x = (unsigned short*)p; p += (size_t)NU * HID * 2;
    unsigned short* mean2  = (unsigned short*)p; p += (size_t)NM * HID * 2;
    unsigned short* movie_z= (unsigned short*)p; p += (size_t)NM * HID * 2;
    unsigned short* mean3  = (unsigned short*)p; p += (size_t)NU * HID * 2;

    // ---- CSR build ----
    hipMemsetAsync(ghist, 0, NBUCK * sizeof(int), stream);
    k_hist<<<NPBLK, 256, 0, stream>>>(user_idx, movie_idx, ghist);
    k_bscan<<<1, 512, 0, stream>>>(ghist, bb, gcur);
    k_part<<<NPBLK, 256, 0, stream>>>(user_idx, movie_idx, gcur, entries);
    k_csr<<<NBUCK, 256, 0, stream>>>(bb, entries, rp, list);

    // ---- conversions + c1 ----
    k_cvt<<<(CVT_TOT + 255) / 256, 256, 0, stream>>>(W1l, W2l, W2r, W3l, W3r,
                                                     Wlin1, Wlin2, movie_x, wb);
    k_c1<<<1, 128, 0, stream>>>(user_emb, W1r, b1, c1);

    // ---- conv1: gather + GEMM -> user_x ----
    k_gather_b<FEAT><<<(NU + 31) / 32, 256, 0, stream>>>(mxb, rp, list, mean1, 0, NU);
    k_mf2<FEAT, HID, true, true, false><<<(NU + 127) / 128, 256, 0, stream>>>(
        mean1, W1l_b, c1, user_x, NU);

    // ---- conv2 + lin2 (fused movie chain) ----
    k_gather_b<HID><<<(NM + 15) / 16, 256, 0, stream>>>(user_x, rp, list, mean2, NU, NM);
    k_fused_m<<<(NM + 127) / 128, 256, 0, stream>>>(
        mean2, mxb, W2l_b, W2r_b, b2, movie_z, Wlin2_b, blin2,
        out + (size_t)NU * OUTD, NM);

    // ---- conv3 + lin1 (fused user chain; t3 computed inline from user_x) ----
    k_gather_b<HID><<<(NU + 15) / 16, 256, 0, stream>>>(movie_z, rp, list, mean3, 0, NU);
    k_fused_u<<<(NU + 127) / 128, 256, 0, stream>>>(
        mean3, user_x, W3l_b, W3r_b, b3, Wlin1_b, blin1, out, NU);

    // ---- new_index ----
    k_index<<<(100000 + 255) / 256, 256, 0, stream>>>(
        tuples, out + (size_t)(NU + NM) * OUTD, 100000, NU);
}